// Round 1
// baseline (2911.892 us; speedup 1.0000x reference)
//
#include <hip/hip_runtime.h>

// Problem constants (Transformer-XL attention)
constexpr int BSZ  = 4;
constexpr int NH   = 16;
constexpr int DH   = 64;
constexpr int QL   = 1024;
constexpr int KLN  = 2048;
constexpr int DM   = 1024;   // d_model = NH*DH
constexpr int MEM  = 1024;   // KLEN - QLEN

// ---------------------------------------------------------------------------
// Generic tiled fp32 GEMM: C[M,N] = A[M,K] @ B[K,N], row-major.
// Batched over blockIdx.z with strides sA (A) and sC (C); B shared.
// BM=BN=64, BK=16, 256 threads, 4x4 micro-tile per thread.
// ---------------------------------------------------------------------------
__global__ __launch_bounds__(256)
void gemm_f32(const float* __restrict__ A, const float* __restrict__ B,
              float* __restrict__ C, int M, int N, int K, long sA, long sC)
{
    constexpr int BM = 64, BN = 64, BK = 16, ST = 68; // ST: padded LDS stride
    __shared__ __align__(16) float As[BK][ST];  // As[k][m] (transposed store)
    __shared__ __align__(16) float Bs[BK][ST];  // Bs[k][n]

    const int z = blockIdx.z;
    A += (long)z * sA;
    C += (long)z * sC;
    const int n0 = blockIdx.x * BN;
    const int m0 = blockIdx.y * BM;
    const int tid = threadIdx.x;
    const int tx = tid & 15, ty = tid >> 4;
    const int arow = tid >> 2, ak = (tid & 3) << 2;    // A tile: 64 rows x 16 k
    const int brow = tid >> 4, bcol = (tid & 15) << 2; // B tile: 16 rows x 64 n

    float acc[4][4] = {};

    for (int k0 = 0; k0 < K; k0 += BK) {
        float4 av = *(const float4*)(A + (long)(m0 + arow) * K + k0 + ak);
        float4 bv = *(const float4*)(B + (long)(k0 + brow) * N + n0 + bcol);
        As[ak + 0][arow] = av.x;
        As[ak + 1][arow] = av.y;
        As[ak + 2][arow] = av.z;
        As[ak + 3][arow] = av.w;
        *(float4*)&Bs[brow][bcol] = bv;
        __syncthreads();
#pragma unroll
        for (int kk = 0; kk < BK; ++kk) {
            float4 a4 = *(const float4*)&As[kk][ty << 2];
            float4 b4 = *(const float4*)&Bs[kk][tx << 2];
            float am[4] = {a4.x, a4.y, a4.z, a4.w};
            float bm[4] = {b4.x, b4.y, b4.z, b4.w};
#pragma unroll
            for (int i = 0; i < 4; ++i)
#pragma unroll
                for (int j = 0; j < 4; ++j)
                    acc[i][j] = fmaf(am[i], bm[j], acc[i][j]);
        }
        __syncthreads();
    }
#pragma unroll
    for (int i = 0; i < 4; ++i) {
        float4 o = {acc[i][0], acc[i][1], acc[i][2], acc[i][3]};
        *(float4*)(C + (long)(m0 + (ty << 2) + i) * N + n0 + (tx << 2)) = o;
    }
}

// ---------------------------------------------------------------------------
// Flash-style XL attention.
//   q  : [B][QL][NH*DH]    (w[:, -qlen:] @ Wq)
//   kv : [B][KLN][2*NH*DH] (k cols 0..1023, v cols 1024..2047)
//   rkm: [KLN][NH*DH]      (r @ Wr)
//   av : [B][QL][NH*DH]    output attn_vec
// Unmasked region: S[i][j] = (q_i+bw)·k_j + (q_i+br)·rk[j - i + QL - 1], *scale
// Mask: j > i + MEM -> -1e30. Softmax over j, online.
// Block: 256 threads handles BI=32 query rows of one (b, head).
// ---------------------------------------------------------------------------
constexpr int BI  = 32;
constexpr int BJ  = 64;
constexpr int RKR = 96;  // shifted-rk tile rows: (BJ-1)-(-(BI-1)) + 1 = 95 -> 96
constexpr int ST  = 68;  // padded LDS row stride (floats), 16B-multiple

__global__ __launch_bounds__(256)
void attn_xl(const float* __restrict__ q, const float* __restrict__ kv,
             const float* __restrict__ rkm, const float* __restrict__ bw,
             const float* __restrict__ br, float* __restrict__ av)
{
    extern __shared__ __align__(16) float smem[];
    float (*qw)[ST]  = (float(*)[ST])smem;      // [BI][ST]  q + r_w_bias
    float (*qr)[ST]  = qw + BI;                 // [BI][ST]  q + r_r_bias
    float (*kt)[ST]  = qr + BI;                 // [BJ][ST]
    float (*vt)[ST]  = kt + BJ;                 // [BJ][ST]
    float (*rkt)[ST] = vt + BJ;                 // [RKR][ST]
    float (*ps)[ST]  = rkt + RKR;               // [BI][ST]  P tile
    float (*red)[17] = (float(*)[17])(ps + BI); // [BI][17] reduction scratch
    float* m_s  = (float*)(red + BI);
    float* l_s  = m_s + BI;
    float* al_s = l_s + BI;

    const int i0  = blockIdx.x * BI;
    const int n   = blockIdx.y;
    const int b   = blockIdx.z;
    const int tid = threadIdx.x;
    const int tx  = tid & 15, ty = tid >> 4;
    const int il0 = ty << 1;            // this thread's 2 query rows: il0, il0+1
    const float scale = 0.125f;         // 1/sqrt(64)

    // ---- load q tiles (+bias): 2 tiles x 32 rows x 64 = 128 tasks of 16 floats
    {
        const int which = tid >> 7, t = tid & 127;
        const int row = t >> 2, seg = (t & 3) << 4;
        const float* bias = (which ? br : bw) + n * DH + seg;
        const float* src  = q + ((long)(b * QL + i0 + row)) * DM + n * DH + seg;
        float* dst = which ? &qr[row][seg] : &qw[row][seg];
#pragma unroll
        for (int u = 0; u < 16; u += 4) {
            float4 a = *(const float4*)(src + u);
            float4 c = *(const float4*)(bias + u);
            dst[u + 0] = a.x + c.x;
            dst[u + 1] = a.y + c.y;
            dst[u + 2] = a.z + c.z;
            dst[u + 3] = a.w + c.w;
        }
    }
    if (tid < BI) { m_s[tid] = -1e30f; l_s[tid] = 0.f; }

    float acc[2][4] = {};  // O accumulator: rows {il0,il0+1} x cols {tx*4..tx*4+3}

    // j-tiles needed: j <= i0+BI-1+MEM
    const int ntiles = (i0 + BI - 1 + MEM + BJ) / BJ;

    for (int jt = 0; jt < ntiles; ++jt) {
        const int j0 = jt * BJ;
        const int rbase = j0 - i0 + (QL - 1) - (BI - 1);  // rk row of rkt[0]
        __syncthreads();  // previous tile's PV done before overwriting tiles

        // ---- stage k/v tile: 64 rows x 4 segs, one 16-float task per thread
        {
            const int row = tid >> 2, seg = (tid & 3) << 4;
            const float* kb = kv + ((long)(b * KLN + j0 + row)) * (2 * DM) + n * DH + seg;
#pragma unroll
            for (int u = 0; u < 16; u += 4) {
                *(float4*)&kt[row][seg + u] = *(const float4*)(kb + u);
                *(float4*)&vt[row][seg + u] = *(const float4*)(kb + DM + u);
            }
        }
        // ---- stage shifted rk tile: 96 rows x 4 segs = 384 tasks
        for (int t = tid; t < RKR * 4; t += 256) {
            const int row = t >> 2, seg = (t & 3) << 4;
            int rr = rbase + row;
            rr = rr < 0 ? 0 : (rr > KLN - 1 ? KLN - 1 : rr);  // OOB only if masked
            const float* rb = rkm + (long)rr * DM + n * DH + seg;
#pragma unroll
            for (int u = 0; u < 16; u += 4)
                *(float4*)&rkt[row][seg + u] = *(const float4*)(rb + u);
        }
        __syncthreads();

        // ---- S tile: rows {il0,il0+1}, cols {rj*16+tx}
        float s[2][4] = {};
#pragma unroll 4
        for (int d = 0; d < DH; d += 4) {
            float4 w0 = *(const float4*)&qw[il0 + 0][d];
            float4 w1 = *(const float4*)&qw[il0 + 1][d];
            float4 r0q = *(const float4*)&qr[il0 + 0][d];
            float4 r1q = *(const float4*)&qr[il0 + 1][d];
#pragma unroll
            for (int rj = 0; rj < 4; ++rj) {
                const int jl = (rj << 4) + tx;
                float4 k4 = *(const float4*)&kt[jl][d];
                s[0][rj] += w0.x * k4.x + w0.y * k4.y + w0.z * k4.z + w0.w * k4.w;
                s[1][rj] += w1.x * k4.x + w1.y * k4.y + w1.z * k4.z + w1.w * k4.w;
                // rkt row = jl - il + (BI-1)
                float4 g0 = *(const float4*)&rkt[jl - il0 + (BI - 1)][d];
                float4 g1 = *(const float4*)&rkt[jl - il0 + (BI - 2)][d];
                s[0][rj] += r0q.x * g0.x + r0q.y * g0.y + r0q.z * g0.z + r0q.w * g0.w;
                s[1][rj] += r1q.x * g1.x + r1q.y * g1.y + r1q.z * g1.z + r1q.w * g1.w;
            }
        }
        // ---- mask + scale
#pragma unroll
        for (int ri = 0; ri < 2; ++ri) {
            const int gi = i0 + il0 + ri;
#pragma unroll
            for (int rj = 0; rj < 4; ++rj) {
                const int gj = j0 + (rj << 4) + tx;
                s[ri][rj] = (gj > gi + MEM) ? -1e30f : s[ri][rj] * scale;
            }
        }
        // ---- row-max partials
#pragma unroll
        for (int ri = 0; ri < 2; ++ri)
            red[il0 + ri][tx] = fmaxf(fmaxf(s[ri][0], s[ri][1]),
                                      fmaxf(s[ri][2], s[ri][3]));
        __syncthreads();
        if (tid < BI) {
            float mo = m_s[tid], mn = mo;
#pragma unroll
            for (int c = 0; c < 16; ++c) mn = fmaxf(mn, red[tid][c]);
            m_s[tid]  = mn;
            al_s[tid] = __expf(mo - mn);  // mo==mn==-1e30 -> 1.0 (harmless, l=0)
        }
        __syncthreads();
        // ---- P = exp(S - m), rescale O, partial row sums
#pragma unroll
        for (int ri = 0; ri < 2; ++ri) {
            const int gi   = i0 + il0 + ri;
            const float mn = m_s[il0 + ri];
            const float a  = al_s[il0 + ri];
            float psum = 0.f;
#pragma unroll
            for (int rj = 0; rj < 4; ++rj) {
                acc[ri][rj] *= a;
                const int gj = j0 + (rj << 4) + tx;
                float p = (gj > gi + MEM) ? 0.f : __expf(s[ri][rj] - mn);
                ps[il0 + ri][(rj << 4) + tx] = p;
                psum += p;
            }
            red[il0 + ri][tx] = psum;
        }
        __syncthreads();
        if (tid < BI) {
            float ss = 0.f;
#pragma unroll
            for (int c = 0; c < 16; ++c) ss += red[tid][c];
            l_s[tid] = l_s[tid] * al_s[tid] + ss;
        }
        // ---- O += P @ V (cols d = tx*4 + comp)
#pragma unroll 8
        for (int j = 0; j < BJ; ++j) {
            float4 vv = *(const float4*)&vt[j][tx << 2];
            float p0 = ps[il0 + 0][j];
            float p1 = ps[il0 + 1][j];
            acc[0][0] += p0 * vv.x; acc[0][1] += p0 * vv.y;
            acc[0][2] += p0 * vv.z; acc[0][3] += p0 * vv.w;
            acc[1][0] += p1 * vv.x; acc[1][1] += p1 * vv.y;
            acc[1][2] += p1 * vv.z; acc[1][3] += p1 * vv.w;
        }
    }
    __syncthreads();  // l_s finalized
#pragma unroll
    for (int ri = 0; ri < 2; ++ri) {
        const float inv = 1.0f / l_s[il0 + ri];
        float4 o = {acc[ri][0] * inv, acc[ri][1] * inv,
                    acc[ri][2] * inv, acc[ri][3] * inv};
        *(float4*)(av + ((long)(b * QL + i0 + il0 + ri)) * DM + n * DH + (tx << 2)) = o;
    }
}

// ---------------------------------------------------------------------------
// Launch: q/kv/rk GEMMs -> flash attention -> output GEMM.
// Workspace layout (floats): q 4M | kv 16M | rk 2M | av 4M  = 104 MB.
// ---------------------------------------------------------------------------
extern "C" void kernel_launch(void* const* d_in, const int* in_sizes, int n_in,
                              void* d_out, int out_size, void* d_ws, size_t ws_size,
                              hipStream_t stream)
{
    const float* w   = (const float*)d_in[0];
    const float* r   = (const float*)d_in[1];
    const float* bwb = (const float*)d_in[2];  // r_w_bias
    const float* brb = (const float*)d_in[3];  // r_r_bias
    const float* Wq  = (const float*)d_in[4];
    const float* Wkv = (const float*)d_in[5];
    const float* Wr  = (const float*)d_in[6];
    const float* Wo  = (const float*)d_in[7];
    // d_in[8] attn_mask: recomputed analytically; d_in[9] qlen: constant 1024.
    float* out = (float*)d_out;

    float* ws    = (float*)d_ws;
    float* q_ws  = ws;                                   //  4M floats
    float* kv_ws = q_ws  + (size_t)BSZ * QL * DM;        // 16M floats
    float* rk_ws = kv_ws + (size_t)BSZ * KLN * 2 * DM;   //  2M floats
    float* av_ws = rk_ws + (size_t)KLN * DM;             //  4M floats

    dim3 blk(256);
    // q = w[:, -QL:] @ Wq       [per batch: 1024x1024x1024]
    gemm_f32<<<dim3(16, 16, 4), blk, 0, stream>>>(
        w + (size_t)MEM * DM, Wq, q_ws, QL, DM, DM,
        (long)KLN * DM, (long)QL * DM);
    // kv = w @ Wkv              [per batch: 2048x2048x1024]
    gemm_f32<<<dim3(32, 32, 4), blk, 0, stream>>>(
        w, Wkv, kv_ws, KLN, 2 * DM, DM,
        (long)KLN * DM, (long)KLN * 2 * DM);
    // rk = r @ Wr               [2048x1024x1024]
    gemm_f32<<<dim3(16, 32, 1), blk, 0, stream>>>(
        r, Wr, rk_ws, KLN, DM, DM, 0, 0);
    // flash attention
    const int attn_lds = (BI * 2 + BJ * 2 + RKR + BI) * ST * 4 + BI * 17 * 4 + 3 * BI * 4;
    attn_xl<<<dim3(QL / BI, NH, BSZ), blk, attn_lds, stream>>>(
        q_ws, kv_ws, rk_ws, bwb, brb, av_ws);
    // out = av @ Wo             [per batch: 1024x1024x1024]
    gemm_f32<<<dim3(16, 16, 4), blk, 0, stream>>>(
        av_ws, Wo, out, QL, DM, DM,
        (long)QL * DM, (long)QL * DM);
}

// Round 2
// 1035.984 us; speedup vs baseline: 2.8107x; 2.8107x over previous
//
#include <hip/hip_runtime.h>

// Problem constants (Transformer-XL attention)
constexpr int BSZ  = 4;
constexpr int NH   = 16;
constexpr int DH   = 64;
constexpr int QL   = 1024;
constexpr int KLN  = 2048;
constexpr int DM   = 1024;   // d_model = NH*DH
constexpr int MEM  = 1024;   // KLEN - QLEN

typedef __bf16 bf16x8  __attribute__((ext_vector_type(8)));
typedef __bf16 bf16x4t __attribute__((ext_vector_type(4)));
typedef float  f32x4   __attribute__((ext_vector_type(4)));

// ---------------------------------------------------------------------------
// Generic tiled fp32 GEMM: C[M,N] = A[M,K] @ B[K,N], row-major (unchanged).
// ---------------------------------------------------------------------------
__global__ __launch_bounds__(256)
void gemm_f32(const float* __restrict__ A, const float* __restrict__ B,
              float* __restrict__ C, int M, int N, int K, long sA, long sC)
{
    constexpr int BK = 16, ST = 68;
    __shared__ __align__(16) float As[BK][ST];
    __shared__ __align__(16) float Bs[BK][ST];

    const int z = blockIdx.z;
    A += (long)z * sA;
    C += (long)z * sC;
    const int n0 = blockIdx.x * 64;
    const int m0 = blockIdx.y * 64;
    const int tid = threadIdx.x;
    const int tx = tid & 15, ty = tid >> 4;
    const int arow = tid >> 2, ak = (tid & 3) << 2;
    const int brow = tid >> 4, bcol = (tid & 15) << 2;

    float acc[4][4] = {};

    for (int k0 = 0; k0 < K; k0 += BK) {
        float4 av = *(const float4*)(A + (long)(m0 + arow) * K + k0 + ak);
        float4 bv = *(const float4*)(B + (long)(k0 + brow) * N + n0 + bcol);
        As[ak + 0][arow] = av.x;
        As[ak + 1][arow] = av.y;
        As[ak + 2][arow] = av.z;
        As[ak + 3][arow] = av.w;
        *(float4*)&Bs[brow][bcol] = bv;
        __syncthreads();
#pragma unroll
        for (int kk = 0; kk < BK; ++kk) {
            float4 a4 = *(const float4*)&As[kk][ty << 2];
            float4 b4 = *(const float4*)&Bs[kk][tx << 2];
            float am[4] = {a4.x, a4.y, a4.z, a4.w};
            float bm[4] = {b4.x, b4.y, b4.z, b4.w};
#pragma unroll
            for (int i = 0; i < 4; ++i)
#pragma unroll
                for (int j = 0; j < 4; ++j)
                    acc[i][j] = fmaf(am[i], bm[j], acc[i][j]);
        }
        __syncthreads();
    }
#pragma unroll
    for (int i = 0; i < 4; ++i) {
        float4 o = {acc[i][0], acc[i][1], acc[i][2], acc[i][3]};
        *(float4*)(C + (long)(m0 + (ty << 2) + i) * N + n0 + (tx << 2)) = o;
    }
}

// ---------------------------------------------------------------------------
// cast_q: q_ws [b][i][n*64+d] f32  ->  qwh/qrh [b][n][i][64] bf16 (+biases)
// ---------------------------------------------------------------------------
__global__ __launch_bounds__(256)
void cast_q(const float* __restrict__ q, const float* __restrict__ bw,
            const float* __restrict__ br, __bf16* __restrict__ qwh,
            __bf16* __restrict__ qrh)
{
    size_t idx = ((size_t)blockIdx.x * 256 + threadIdx.x) * 4;
    int d = idx & 63, n = (idx >> 6) & 15, i = (idx >> 10) & 1023, b = (int)(idx >> 20);
    float4 qv = *(const float4*)(q + idx);
    float4 wv = *(const float4*)(bw + n * 64 + d);
    float4 rv = *(const float4*)(br + n * 64 + d);
    size_t o = ((size_t)((b * 16 + n) * QL + i)) * 64 + d;
    bf16x4t aw = {(__bf16)(qv.x + wv.x), (__bf16)(qv.y + wv.y),
                  (__bf16)(qv.z + wv.z), (__bf16)(qv.w + wv.w)};
    bf16x4t ar = {(__bf16)(qv.x + rv.x), (__bf16)(qv.y + rv.y),
                  (__bf16)(qv.z + rv.z), (__bf16)(qv.w + rv.w)};
    *(bf16x4t*)(qwh + o) = aw;
    *(bf16x4t*)(qrh + o) = ar;
}

// ---------------------------------------------------------------------------
// cast_rk: rk_ws [u][n*64+d] f32 -> rkh [n][u][64] bf16
// ---------------------------------------------------------------------------
__global__ __launch_bounds__(256)
void cast_rk(const float* __restrict__ rk, __bf16* __restrict__ rkh)
{
    size_t idx = ((size_t)blockIdx.x * 256 + threadIdx.x) * 4;
    int d = idx & 63, n = (idx >> 6) & 15, u = (int)(idx >> 10);
    float4 v = *(const float4*)(rk + idx);
    bf16x4t y = {(__bf16)v.x, (__bf16)v.y, (__bf16)v.z, (__bf16)v.w};
    *(bf16x4t*)(rkh + ((size_t)(n * KLN + u)) * 64 + d) = y;
}

// ---------------------------------------------------------------------------
// kv_split: kv_ws [b][j][2*DM] f32 -> kh [b][n][j][64] bf16
//                                      vhT [b][n][64][KLN] bf16 (V transposed)
// One block per (j-block of 64, n, b); LDS transpose for V.
// ---------------------------------------------------------------------------
__global__ __launch_bounds__(256)
void kv_split(const float* __restrict__ kv, __bf16* __restrict__ kh,
              __bf16* __restrict__ vhT)
{
    __shared__ __bf16 lt[64 * 72];
    const int jb = blockIdx.x, n = blockIdx.y, b = blockIdx.z;
    const int tid = threadIdx.x;
    const int jl = tid >> 2, dseg = (tid & 3) << 4;
    const float* src = kv + ((size_t)(b * KLN + jb * 64 + jl)) * (2 * DM) + n * 64 + dseg;
    __bf16* kdst = kh + ((size_t)((b * 16 + n) * KLN + jb * 64 + jl)) * 64 + dseg;
#pragma unroll
    for (int u = 0; u < 16; u += 4) {
        float4 x = *(const float4*)(src + u);
        bf16x4t y = {(__bf16)x.x, (__bf16)x.y, (__bf16)x.z, (__bf16)x.w};
        *(bf16x4t*)(kdst + u) = y;
        float4 vv = *(const float4*)(src + DM + u);
        lt[(dseg + u + 0) * 72 + jl] = (__bf16)vv.x;
        lt[(dseg + u + 1) * 72 + jl] = (__bf16)vv.y;
        lt[(dseg + u + 2) * 72 + jl] = (__bf16)vv.z;
        lt[(dseg + u + 3) * 72 + jl] = (__bf16)vv.w;
    }
    __syncthreads();
    const int dl = tid >> 2, jseg = (tid & 3) << 4;
    __bf16* vdst = vhT + ((size_t)((b * 16 + n) * 64 + dl)) * KLN + jb * 64 + jseg;
    *(uint4*)(vdst)     = *(const uint4*)(lt + dl * 72 + jseg);
    *(uint4*)(vdst + 8) = *(const uint4*)(lt + dl * 72 + jseg + 8);
}

// ---------------------------------------------------------------------------
// MFMA flash attention.  Grid (QL/64, NH, BSZ), 256 threads (4 waves).
// Wave w owns 16 query rows; iterates 64-wide j-tiles.
// S^T[j][i] = K[j]·Qw[i] + rk[j-i+1023]·Qr[i]  via 16x16x32 bf16 MFMA.
// BD via Btilde^T = RK·Qr^T (regular GEMM over u) + per-element LDS gather.
// Online softmax per column i (reg-local + shfl_xor 16/32).
// O^T = V^T·P via MFMA; P round-trips LDS as [i][j] bf16.
// LDS: kt 64x72 | vt 64x72 | rkt 128x72 | pt 4x16x72 | bt 4x80x16  = 56320 B.
// ---------------------------------------------------------------------------
__global__ __launch_bounds__(256, 2)
void attn_mfma(const __bf16* __restrict__ qwh, const __bf16* __restrict__ qrh,
               const __bf16* __restrict__ kh, const __bf16* __restrict__ vhT,
               const __bf16* __restrict__ rkh, float* __restrict__ av)
{
    extern __shared__ __bf16 smem[];
    __bf16* kt  = smem;           // [64][72]
    __bf16* vt  = smem + 4608;    // [64][72]
    __bf16* rkt = smem + 9216;    // [128][72]
    __bf16* pt  = smem + 18432;   // [4][16][72]
    __bf16* bt  = smem + 23040;   // [4][80][16]

    const int i0 = blockIdx.x * 64;
    const int n = blockIdx.y, b = blockIdx.z;
    const int tid = threadIdx.x;
    const int w = tid >> 6, l = tid & 63;
    const int il = l & 15, quad = l >> 4;
    const int iw0 = i0 + w * 16;
    const int i_gl = iw0 + il;     // the query column this lane owns in C frags

    __bf16* ptw = pt + w * 1152;
    __bf16* btw = bt + w * 1280;

    // persistent Q fragments (B-operand: n=i, k=d)
    const size_t qoff = ((size_t)((b * 16 + n) * QL + iw0 + il)) * 64 + quad * 8;
    bf16x8 qwf0 = *(const bf16x8*)(qwh + qoff);
    bf16x8 qwf1 = *(const bf16x8*)(qwh + qoff + 32);
    bf16x8 qrf0 = *(const bf16x8*)(qrh + qoff);
    bf16x8 qrf1 = *(const bf16x8*)(qrh + qoff + 32);

    f32x4 O[4] = {};               // O^T frags: rows d = df*16+quad*4+r, col i
    float m_i = -1e30f, l_i = 0.f;
    const float c = 0.125f * 1.44269504f;   // scale * log2(e)

    const int srow = tid >> 2, sseg = (tid & 3) << 4;
    const int rrow = tid & 127, rseg = (tid >> 7) << 5;
    const __bf16* kbase = kh + ((size_t)((b * 16 + n) * KLN)) * 64;
    const __bf16* vbase = vhT + ((size_t)((b * 16 + n) * 64 + srow)) * KLN;
    const __bf16* rbp   = rkh + ((size_t)(n * KLN)) * 64;
    const int ub = 48 - 16 * w;    // wave's base row inside rkt

    const int ntiles = (i0 + 63 + MEM) / 64 + 1;

    for (int jt = 0; jt < ntiles; ++jt) {
        const int j0 = jt * 64;
        __syncthreads();
        {   // stage K tile [j][d]
            const __bf16* s = kbase + ((size_t)(j0 + srow)) * 64 + sseg;
            __bf16* d0 = kt + srow * 72 + sseg;
            *(uint4*)d0 = *(const uint4*)s;
            *(uint4*)(d0 + 8) = *(const uint4*)(s + 8);
        }
        {   // stage V^T tile [d][j]
            const __bf16* s = vbase + j0 + sseg;
            __bf16* d0 = vt + srow * 72 + sseg;
            *(uint4*)d0 = *(const uint4*)s;
            *(uint4*)(d0 + 8) = *(const uint4*)(s + 8);
        }
        {   // stage rk band: rows u = j0-i0+960 .. +127 (clamped; OOB = masked)
            int u = j0 - i0 + 960 + rrow;
            u = u < 0 ? 0 : (u > KLN - 1 ? KLN - 1 : u);
            const __bf16* s = rbp + (size_t)u * 64 + rseg;
            __bf16* d0 = rkt + rrow * 72 + rseg;
            *(uint4*)(d0)      = *(const uint4*)(s);
            *(uint4*)(d0 + 8)  = *(const uint4*)(s + 8);
            *(uint4*)(d0 + 16) = *(const uint4*)(s + 16);
            *(uint4*)(d0 + 24) = *(const uint4*)(s + 24);
        }
        __syncthreads();

        // ---- AC^T: S^T[j][i] = K·Qw  (4 j-frags x 2 K-steps)
        f32x4 sf[4];
#pragma unroll
        for (int fr = 0; fr < 4; ++fr) {
            const __bf16* ka = kt + (fr * 16 + il) * 72 + quad * 8;
            bf16x8 a0 = *(const bf16x8*)ka;
            bf16x8 a1 = *(const bf16x8*)(ka + 32);
            f32x4 acc = {};
            acc = __builtin_amdgcn_mfma_f32_16x16x32_bf16(a0, qwf0, acc, 0, 0, 0);
            acc = __builtin_amdgcn_mfma_f32_16x16x32_bf16(a1, qwf1, acc, 0, 0, 0);
            sf[fr] = acc;
        }
        // ---- Btilde^T = RK·Qr  (5 u-frags), store to per-wave bt[u][i]
#pragma unroll
        for (int uf = 0; uf < 5; ++uf) {
            const __bf16* ra = rkt + (ub + uf * 16 + il) * 72 + quad * 8;
            bf16x8 a0 = *(const bf16x8*)ra;
            bf16x8 a1 = *(const bf16x8*)(ra + 32);
            f32x4 acc = {};
            acc = __builtin_amdgcn_mfma_f32_16x16x32_bf16(a0, qrf0, acc, 0, 0, 0);
            acc = __builtin_amdgcn_mfma_f32_16x16x32_bf16(a1, qrf1, acc, 0, 0, 0);
            __bf16* bp = btw + (uf * 16 + quad * 4) * 16 + il;
            bp[0]  = (__bf16)acc[0];
            bp[16] = (__bf16)acc[1];
            bp[32] = (__bf16)acc[2];
            bp[48] = (__bf16)acc[3];
        }

        // ---- gather shift + mask; tile max
        float sv[4][4];
        float tmax = -1e30f;
#pragma unroll
        for (int fr = 0; fr < 4; ++fr) {
#pragma unroll
            for (int r = 0; r < 4; ++r) {
                const int jl_ = fr * 16 + quad * 4 + r;
                float s = sf[fr][r] + (float)btw[(jl_ - il + 15) * 16 + il];
                s = (j0 + jl_ > i_gl + MEM) ? -1e30f : s;
                sv[fr][r] = s;
                tmax = fmaxf(tmax, s);
            }
        }
        tmax = fmaxf(tmax, __shfl_xor(tmax, 16));
        tmax = fmaxf(tmax, __shfl_xor(tmax, 32));
        const float m_new = fmaxf(m_i, tmax);
        const float alpha = exp2f((m_i - m_new) * c);
        float psum = 0.f;
#pragma unroll
        for (int fr = 0; fr < 4; ++fr) {
            bf16x4t p4;
#pragma unroll
            for (int r = 0; r < 4; ++r) {
                float p = exp2f((sv[fr][r] - m_new) * c);
                psum += p;
                p4[r] = (__bf16)p;
            }
            *(bf16x4t*)(ptw + il * 72 + fr * 16 + quad * 4) = p4;
        }
        psum += __shfl_xor(psum, 16);
        psum += __shfl_xor(psum, 32);
        l_i = l_i * alpha + psum;
        m_i = m_new;
#pragma unroll
        for (int df = 0; df < 4; ++df) O[df] *= alpha;

        // ---- O^T += V^T · P
        bf16x8 p0 = *(const bf16x8*)(ptw + il * 72 + quad * 8);
        bf16x8 p1 = *(const bf16x8*)(ptw + il * 72 + 32 + quad * 8);
#pragma unroll
        for (int df = 0; df < 4; ++df) {
            const __bf16* va = vt + (df * 16 + il) * 72 + quad * 8;
            bf16x8 a0 = *(const bf16x8*)va;
            bf16x8 a1 = *(const bf16x8*)(va + 32);
            O[df] = __builtin_amdgcn_mfma_f32_16x16x32_bf16(a0, p0, O[df], 0, 0, 0);
            O[df] = __builtin_amdgcn_mfma_f32_16x16x32_bf16(a1, p1, O[df], 0, 0, 0);
        }
    }

    const float inv = 1.0f / l_i;
    float* ob = av + ((size_t)(b * QL + i_gl)) * DM + n * 64 + quad * 4;
#pragma unroll
    for (int df = 0; df < 4; ++df) {
        f32x4 o = O[df] * inv;
        *(f32x4*)(ob + df * 16) = o;
    }
}

// ---------------------------------------------------------------------------
// Workspace layout (140 MB):
//   0   q_ws (16MB, reused as av after cast_q) | 16MB kv_ws (64MB)
//   80  rk_ws (8MB) | 88 qwh (8MB) | 96 qrh (8MB) | 104 kh (16MB)
//   120 vhT (16MB) | 136 rkh (4MB)
// ---------------------------------------------------------------------------
extern "C" void kernel_launch(void* const* d_in, const int* in_sizes, int n_in,
                              void* d_out, int out_size, void* d_ws, size_t ws_size,
                              hipStream_t stream)
{
    const float* w   = (const float*)d_in[0];
    const float* r   = (const float*)d_in[1];
    const float* bwb = (const float*)d_in[2];
    const float* brb = (const float*)d_in[3];
    const float* Wq  = (const float*)d_in[4];
    const float* Wkv = (const float*)d_in[5];
    const float* Wr  = (const float*)d_in[6];
    const float* Wo  = (const float*)d_in[7];
    float* out = (float*)d_out;

    char* ws = (char*)d_ws;
    float*  qav_ws = (float*)(ws);
    float*  kv_ws  = (float*)(ws + ((size_t)16 << 20));
    float*  rk_ws  = (float*)(ws + ((size_t)80 << 20));
    __bf16* qwh    = (__bf16*)(ws + ((size_t)88 << 20));
    __bf16* qrh    = (__bf16*)(ws + ((size_t)96 << 20));
    __bf16* kh     = (__bf16*)(ws + ((size_t)104 << 20));
    __bf16* vhT    = (__bf16*)(ws + ((size_t)120 << 20));
    __bf16* rkh    = (__bf16*)(ws + ((size_t)136 << 20));

    dim3 blk(256);
    gemm_f32<<<dim3(16, 16, 4), blk, 0, stream>>>(
        w + (size_t)MEM * DM, Wq, qav_ws, QL, DM, DM, (long)KLN * DM, (long)QL * DM);
    gemm_f32<<<dim3(32, 32, 4), blk, 0, stream>>>(
        w, Wkv, kv_ws, KLN, 2 * DM, DM, (long)KLN * DM, (long)KLN * 2 * DM);
    gemm_f32<<<dim3(16, 32, 1), blk, 0, stream>>>(
        r, Wr, rk_ws, KLN, DM, DM, 0, 0);
    cast_q<<<4096, blk, 0, stream>>>(qav_ws, bwb, brb, qwh, qrh);
    cast_rk<<<2048, blk, 0, stream>>>(rk_ws, rkh);
    kv_split<<<dim3(32, 16, 4), blk, 0, stream>>>(kv_ws, kh, vhT);
    attn_mfma<<<dim3(16, 16, 4), blk, 56320, stream>>>(qwh, qrh, kh, vhT, rkh, qav_ws);
    gemm_f32<<<dim3(16, 16, 4), blk, 0, stream>>>(
        qav_ws, Wo, out, QL, DM, DM, (long)QL * DM, (long)QL * DM);
}

// Round 3
// 446.967 us; speedup vs baseline: 6.5148x; 2.3178x over previous
//
#include <hip/hip_runtime.h>

// Problem constants (Transformer-XL attention)
constexpr int BSZ  = 4;
constexpr int NH   = 16;
constexpr int DH   = 64;
constexpr int QL   = 1024;
constexpr int KLN  = 2048;
constexpr int DM   = 1024;   // d_model = NH*DH
constexpr int MEM  = 1024;   // KLEN - QLEN

typedef __bf16 bf16x8  __attribute__((ext_vector_type(8)));
typedef __bf16 bf16x4t __attribute__((ext_vector_type(4)));
typedef float  f32x4   __attribute__((ext_vector_type(4)));

// async global->LDS, 16B per lane; LDS dst is wave-uniform base + lane*16
__device__ __forceinline__ void g2l16(__bf16* lds, const __bf16* g) {
    __builtin_amdgcn_global_load_lds(
        (const __attribute__((address_space(1))) unsigned int*)g,
        (__attribute__((address_space(3))) unsigned int*)lds, 16, 0, 0);
}

// ---------------------------------------------------------------------------
// cast f32 -> bf16, same layout. 8 elems/thread.
// ---------------------------------------------------------------------------
__global__ __launch_bounds__(256)
void cast_bf16(const float* __restrict__ in, __bf16* __restrict__ out)
{
    size_t i = ((size_t)blockIdx.x * 256 + threadIdx.x) * 8;
    float4 a = *(const float4*)(in + i);
    float4 b = *(const float4*)(in + i + 4);
    bf16x8 y = {(__bf16)a.x, (__bf16)a.y, (__bf16)a.z, (__bf16)a.w,
                (__bf16)b.x, (__bf16)b.y, (__bf16)b.z, (__bf16)b.w};
    *(bf16x8*)(out + i) = y;
}

// ---------------------------------------------------------------------------
// transpose-cast: in f32 [K][N] -> out bf16 [N][K].  64x64 tiles, 256 thr.
// ---------------------------------------------------------------------------
__global__ __launch_bounds__(256)
void tcast(const float* __restrict__ in, __bf16* __restrict__ out, int K, int N)
{
    __shared__ __bf16 t[64 * 72];
    const int n0 = blockIdx.x * 64, k0 = blockIdx.y * 64;
    const int row = threadIdx.x >> 2, seg = (threadIdx.x & 3) << 4;
    const float* src = in + (long)(k0 + row) * N + n0 + seg;
#pragma unroll
    for (int u = 0; u < 16; u += 4) {
        float4 x = *(const float4*)(src + u);
        t[(seg + u + 0) * 72 + row] = (__bf16)x.x;
        t[(seg + u + 1) * 72 + row] = (__bf16)x.y;
        t[(seg + u + 2) * 72 + row] = (__bf16)x.z;
        t[(seg + u + 3) * 72 + row] = (__bf16)x.w;
    }
    __syncthreads();
    __bf16* dst = out + (long)(n0 + row) * K + k0 + seg;
    *(uint4*)(dst)     = *(const uint4*)(t + row * 72 + seg);
    *(uint4*)(dst + 8) = *(const uint4*)(t + row * 72 + seg + 8);
}

// ---------------------------------------------------------------------------
// bf16 MFMA GEMM: C[M,N] = A[M,K] @ BT[N,K]^T.  Tile 128x128, BK=32.
// 256 threads = 4 waves (2x2 of 64x64, 4x4 frags of 16x16x32 each).
// global_load_lds staging with XOR-4 k-chunk swizzle (2-way LDS alias = free).
// C store: bf16 (half_out) or f32.
// ---------------------------------------------------------------------------
__global__ __launch_bounds__(256, 2)
void gemm_bf16(const __bf16* __restrict__ A, const __bf16* __restrict__ BT,
               void* __restrict__ Cv, int M, int N, int K,
               long sA, long sC, int half_out)
{
    __shared__ __bf16 As[128 * 32];
    __shared__ __bf16 Bs[128 * 32];
    const int z = blockIdx.z;
    A += (long)z * sA;
    const int m0 = blockIdx.y * 128, n0 = blockIdx.x * 128;
    const int tid = threadIdx.x, w = tid >> 6, l = tid & 63;
    const int il = l & 15, quad = l >> 4;
    const int wm = (w >> 1) * 64, wn = (w & 1) * 64;
    // staging lane map: row lr, src k-chunk = (l&3) ^ (lr&3)  (XOR swizzle)
    const int lr = l >> 2, kc = (l & 3) ^ (lr & 3);

    const __bf16* ag = A  + (long)(m0 + w * 32 + lr) * K + kc * 8;
    const __bf16* bg = BT + (long)(n0 + w * 32 + lr) * K + kc * 8;
    __bf16* al0 = As + (w * 32) * 32;        // wave-uniform LDS bases
    __bf16* al1 = As + (w * 32 + 16) * 32;
    __bf16* bl0 = Bs + (w * 32) * 32;
    __bf16* bl1 = Bs + (w * 32 + 16) * 32;

    f32x4 acc[4][4] = {};
    const int rsw = (il & 3);                 // read-side swizzle key

    for (int k0 = 0; k0 < K; k0 += 32) {
        __syncthreads();
        g2l16(al0, ag + k0);
        g2l16(al1, ag + k0 + 16 * K);
        g2l16(bl0, bg + k0);
        g2l16(bl1, bg + k0 + 16 * K);
        __syncthreads();

        bf16x8 af[4], bf[4];
#pragma unroll
        for (int f = 0; f < 4; ++f) {
            af[f] = *(const bf16x8*)(As + (wm + f * 16 + il) * 32 + ((quad ^ rsw) << 3));
            bf[f] = *(const bf16x8*)(Bs + (wn + f * 16 + il) * 32 + ((quad ^ rsw) << 3));
        }
#pragma unroll
        for (int i = 0; i < 4; ++i)
#pragma unroll
            for (int j = 0; j < 4; ++j)
                acc[i][j] = __builtin_amdgcn_mfma_f32_16x16x32_bf16(
                    af[i], bf[j], acc[i][j], 0, 0, 0);
    }

    // epilogue: lane holds rows m = quad*4 + r, col n = il of each 16x16 frag
    if (half_out) {
        __bf16* C = (__bf16*)Cv + (long)z * sC;
#pragma unroll
        for (int i = 0; i < 4; ++i)
#pragma unroll
            for (int j = 0; j < 4; ++j) {
                __bf16* cp = C + (long)(m0 + wm + i * 16 + quad * 4) * N
                               + n0 + wn + j * 16 + il;
#pragma unroll
                for (int r = 0; r < 4; ++r) cp[(long)r * N] = (__bf16)acc[i][j][r];
            }
    } else {
        float* C = (float*)Cv + (long)z * sC;
#pragma unroll
        for (int i = 0; i < 4; ++i)
#pragma unroll
            for (int j = 0; j < 4; ++j) {
                float* cp = C + (long)(m0 + wm + i * 16 + quad * 4) * N
                              + n0 + wn + j * 16 + il;
#pragma unroll
                for (int r = 0; r < 4; ++r) cp[(long)r * N] = acc[i][j][r];
            }
    }
}

// ---------------------------------------------------------------------------
// cast_q: qh [b][i][n*64+d] bf16 -> qwh/qrh [b][n][i][64] bf16 (+f32 biases)
// ---------------------------------------------------------------------------
__global__ __launch_bounds__(256)
void cast_q(const __bf16* __restrict__ q, const float* __restrict__ bw,
            const float* __restrict__ br, __bf16* __restrict__ qwh,
            __bf16* __restrict__ qrh)
{
    size_t idx = ((size_t)blockIdx.x * 256 + threadIdx.x) * 8;
    int d = idx & 63, n = (idx >> 6) & 15, i = (idx >> 10) & 1023, b = (int)(idx >> 20);
    bf16x8 qv = *(const bf16x8*)(q + idx);
    size_t o = ((size_t)((b * 16 + n) * QL + i)) * 64 + d;
    bf16x8 aw, ar;
#pragma unroll
    for (int u = 0; u < 8; ++u) {
        float qf = (float)qv[u];
        aw[u] = (__bf16)(qf + bw[n * 64 + d + u]);
        ar[u] = (__bf16)(qf + br[n * 64 + d + u]);
    }
    *(bf16x8*)(qwh + o) = aw;
    *(bf16x8*)(qrh + o) = ar;
}

// ---------------------------------------------------------------------------
// cast_rk: rkf [u][n*64+d] bf16 -> rkh [n][u][64] bf16
// ---------------------------------------------------------------------------
__global__ __launch_bounds__(256)
void cast_rk(const __bf16* __restrict__ rk, __bf16* __restrict__ rkh)
{
    size_t idx = ((size_t)blockIdx.x * 256 + threadIdx.x) * 8;
    int d = idx & 63, n = (idx >> 6) & 15, u = (int)(idx >> 10);
    bf16x8 v = *(const bf16x8*)(rk + idx);
    *(bf16x8*)(rkh + ((size_t)(n * KLN + u)) * 64 + d) = v;
}

// ---------------------------------------------------------------------------
// kv_split: kvh [b][j][2*DM] bf16 -> kh [b][n][j][64] bf16
//                                     vhT [b][n][64][KLN] bf16 (V transposed)
// ---------------------------------------------------------------------------
__global__ __launch_bounds__(256)
void kv_split(const __bf16* __restrict__ kv, __bf16* __restrict__ kh,
              __bf16* __restrict__ vhT)
{
    __shared__ __bf16 lt[64 * 72];
    const int jb = blockIdx.x, n = blockIdx.y, b = blockIdx.z;
    const int tid = threadIdx.x;
    const int jl = tid >> 2, dseg = (tid & 3) << 4;
    const __bf16* src = kv + ((size_t)(b * KLN + jb * 64 + jl)) * (2 * DM) + n * 64 + dseg;
    __bf16* kdst = kh + ((size_t)((b * 16 + n) * KLN + jb * 64 + jl)) * 64 + dseg;
    *(uint4*)(kdst)     = *(const uint4*)(src);
    *(uint4*)(kdst + 8) = *(const uint4*)(src + 8);
#pragma unroll
    for (int u = 0; u < 16; ++u)
        lt[(dseg + u) * 72 + jl] = src[DM + u];
    __syncthreads();
    const int dl = tid >> 2, jseg = (tid & 3) << 4;
    __bf16* vdst = vhT + ((size_t)((b * 16 + n) * 64 + dl)) * KLN + jb * 64 + jseg;
    *(uint4*)(vdst)     = *(const uint4*)(lt + dl * 72 + jseg);
    *(uint4*)(vdst + 8) = *(const uint4*)(lt + dl * 72 + jseg + 8);
}

// ---------------------------------------------------------------------------
// MFMA flash attention (unchanged math; output now bf16).
// LDS: kt 64x72 | vt 64x72 | rkt 128x72 | pt 4x16x72 | bt 4x80x16 = 56320 B.
// ---------------------------------------------------------------------------
__global__ __launch_bounds__(256, 2)
void attn_mfma(const __bf16* __restrict__ qwh, const __bf16* __restrict__ qrh,
               const __bf16* __restrict__ kh, const __bf16* __restrict__ vhT,
               const __bf16* __restrict__ rkh, __bf16* __restrict__ av)
{
    extern __shared__ __bf16 smem[];
    __bf16* kt  = smem;           // [64][72]
    __bf16* vt  = smem + 4608;    // [64][72]
    __bf16* rkt = smem + 9216;    // [128][72]
    __bf16* pt  = smem + 18432;   // [4][16][72]
    __bf16* bt  = smem + 23040;   // [4][80][16]

    const int i0 = blockIdx.x * 64;
    const int n = blockIdx.y, b = blockIdx.z;
    const int tid = threadIdx.x;
    const int w = tid >> 6, l = tid & 63;
    const int il = l & 15, quad = l >> 4;
    const int iw0 = i0 + w * 16;
    const int i_gl = iw0 + il;

    __bf16* ptw = pt + w * 1152;
    __bf16* btw = bt + w * 1280;

    const size_t qoff = ((size_t)((b * 16 + n) * QL + iw0 + il)) * 64 + quad * 8;
    bf16x8 qwf0 = *(const bf16x8*)(qwh + qoff);
    bf16x8 qwf1 = *(const bf16x8*)(qwh + qoff + 32);
    bf16x8 qrf0 = *(const bf16x8*)(qrh + qoff);
    bf16x8 qrf1 = *(const bf16x8*)(qrh + qoff + 32);

    f32x4 O[4] = {};
    float m_i = -1e30f, l_i = 0.f;
    const float c = 0.125f * 1.44269504f;

    const int srow = tid >> 2, sseg = (tid & 3) << 4;
    const int rrow = tid & 127, rseg = (tid >> 7) << 5;
    const __bf16* kbase = kh + ((size_t)((b * 16 + n) * KLN)) * 64;
    const __bf16* vbase = vhT + ((size_t)((b * 16 + n) * 64 + srow)) * KLN;
    const __bf16* rbp   = rkh + ((size_t)(n * KLN)) * 64;
    const int ub = 48 - 16 * w;

    const int ntiles = (i0 + 63 + MEM) / 64 + 1;

    for (int jt = 0; jt < ntiles; ++jt) {
        const int j0 = jt * 64;
        __syncthreads();
        {
            const __bf16* s = kbase + ((size_t)(j0 + srow)) * 64 + sseg;
            __bf16* d0 = kt + srow * 72 + sseg;
            *(uint4*)d0 = *(const uint4*)s;
            *(uint4*)(d0 + 8) = *(const uint4*)(s + 8);
        }
        {
            const __bf16* s = vbase + j0 + sseg;
            __bf16* d0 = vt + srow * 72 + sseg;
            *(uint4*)d0 = *(const uint4*)s;
            *(uint4*)(d0 + 8) = *(const uint4*)(s + 8);
        }
        {
            int u = j0 - i0 + 960 + rrow;
            u = u < 0 ? 0 : (u > KLN - 1 ? KLN - 1 : u);
            const __bf16* s = rbp + (size_t)u * 64 + rseg;
            __bf16* d0 = rkt + rrow * 72 + rseg;
            *(uint4*)(d0)      = *(const uint4*)(s);
            *(uint4*)(d0 + 8)  = *(const uint4*)(s + 8);
            *(uint4*)(d0 + 16) = *(const uint4*)(s + 16);
            *(uint4*)(d0 + 24) = *(const uint4*)(s + 24);
        }
        __syncthreads();

        f32x4 sf[4];
#pragma unroll
        for (int fr = 0; fr < 4; ++fr) {
            const __bf16* ka = kt + (fr * 16 + il) * 72 + quad * 8;
            bf16x8 a0 = *(const bf16x8*)ka;
            bf16x8 a1 = *(const bf16x8*)(ka + 32);
            f32x4 acc = {};
            acc = __builtin_amdgcn_mfma_f32_16x16x32_bf16(a0, qwf0, acc, 0, 0, 0);
            acc = __builtin_amdgcn_mfma_f32_16x16x32_bf16(a1, qwf1, acc, 0, 0, 0);
            sf[fr] = acc;
        }
#pragma unroll
        for (int uf = 0; uf < 5; ++uf) {
            const __bf16* ra = rkt + (ub + uf * 16 + il) * 72 + quad * 8;
            bf16x8 a0 = *(const bf16x8*)ra;
            bf16x8 a1 = *(const bf16x8*)(ra + 32);
            f32x4 acc = {};
            acc = __builtin_amdgcn_mfma_f32_16x16x32_bf16(a0, qrf0, acc, 0, 0, 0);
            acc = __builtin_amdgcn_mfma_f32_16x16x32_bf16(a1, qrf1, acc, 0, 0, 0);
            __bf16* bp = btw + (uf * 16 + quad * 4) * 16 + il;
            bp[0]  = (__bf16)acc[0];
            bp[16] = (__bf16)acc[1];
            bp[32] = (__bf16)acc[2];
            bp[48] = (__bf16)acc[3];
        }

        float sv[4][4];
        float tmax = -1e30f;
#pragma unroll
        for (int fr = 0; fr < 4; ++fr) {
#pragma unroll
            for (int r = 0; r < 4; ++r) {
                const int jl_ = fr * 16 + quad * 4 + r;
                float s = sf[fr][r] + (float)btw[(jl_ - il + 15) * 16 + il];
                s = (j0 + jl_ > i_gl + MEM) ? -1e30f : s;
                sv[fr][r] = s;
                tmax = fmaxf(tmax, s);
            }
        }
        tmax = fmaxf(tmax, __shfl_xor(tmax, 16));
        tmax = fmaxf(tmax, __shfl_xor(tmax, 32));
        const float m_new = fmaxf(m_i, tmax);
        const float alpha = exp2f((m_i - m_new) * c);
        float psum = 0.f;
#pragma unroll
        for (int fr = 0; fr < 4; ++fr) {
            bf16x4t p4;
#pragma unroll
            for (int r = 0; r < 4; ++r) {
                float p = exp2f((sv[fr][r] - m_new) * c);
                psum += p;
                p4[r] = (__bf16)p;
            }
            *(bf16x4t*)(ptw + il * 72 + fr * 16 + quad * 4) = p4;
        }
        psum += __shfl_xor(psum, 16);
        psum += __shfl_xor(psum, 32);
        l_i = l_i * alpha + psum;
        m_i = m_new;
#pragma unroll
        for (int df = 0; df < 4; ++df) O[df] *= alpha;

        bf16x8 p0 = *(const bf16x8*)(ptw + il * 72 + quad * 8);
        bf16x8 p1 = *(const bf16x8*)(ptw + il * 72 + 32 + quad * 8);
#pragma unroll
        for (int df = 0; df < 4; ++df) {
            const __bf16* va = vt + (df * 16 + il) * 72 + quad * 8;
            bf16x8 a0 = *(const bf16x8*)va;
            bf16x8 a1 = *(const bf16x8*)(va + 32);
            O[df] = __builtin_amdgcn_mfma_f32_16x16x32_bf16(a0, p0, O[df], 0, 0, 0);
            O[df] = __builtin_amdgcn_mfma_f32_16x16x32_bf16(a1, p1, O[df], 0, 0, 0);
        }
    }

    const float inv = 1.0f / l_i;
    __bf16* ob = av + ((size_t)(b * QL + i_gl)) * DM + n * 64 + quad * 4;
#pragma unroll
    for (int df = 0; df < 4; ++df) {
        f32x4 o = O[df] * inv;
        bf16x4t y = {(__bf16)o[0], (__bf16)o[1], (__bf16)o[2], (__bf16)o[3]};
        *(bf16x4t*)(ob + df * 16) = y;
    }
}

// ---------------------------------------------------------------------------
// Workspace (MB offsets, 134 MB total):
//  0 wbh | 16 rbh | 20 WqT | 22 WkvT | 26 WrT | 28 WoT | 30 qh | 38 kvh
//  70 rkf | 74 qwh | 82 qrh | 90 kh | 106 vhT | 122 rkh | 126 avh
// ---------------------------------------------------------------------------
extern "C" void kernel_launch(void* const* d_in, const int* in_sizes, int n_in,
                              void* d_out, int out_size, void* d_ws, size_t ws_size,
                              hipStream_t stream)
{
    const float* w   = (const float*)d_in[0];
    const float* r   = (const float*)d_in[1];
    const float* bwb = (const float*)d_in[2];
    const float* brb = (const float*)d_in[3];
    const float* Wq  = (const float*)d_in[4];
    const float* Wkv = (const float*)d_in[5];
    const float* Wr  = (const float*)d_in[6];
    const float* Wo  = (const float*)d_in[7];
    float* out = (float*)d_out;

    char* ws = (char*)d_ws;
    __bf16* wbh  = (__bf16*)(ws);
    __bf16* rbh  = (__bf16*)(ws + ((size_t)16 << 20));
    __bf16* WqT  = (__bf16*)(ws + ((size_t)20 << 20));
    __bf16* WkvT = (__bf16*)(ws + ((size_t)22 << 20));
    __bf16* WrT  = (__bf16*)(ws + ((size_t)26 << 20));
    __bf16* WoT  = (__bf16*)(ws + ((size_t)28 << 20));
    __bf16* qh   = (__bf16*)(ws + ((size_t)30 << 20));
    __bf16* kvh  = (__bf16*)(ws + ((size_t)38 << 20));
    __bf16* rkf  = (__bf16*)(ws + ((size_t)70 << 20));
    __bf16* qwh  = (__bf16*)(ws + ((size_t)74 << 20));
    __bf16* qrh  = (__bf16*)(ws + ((size_t)82 << 20));
    __bf16* kh   = (__bf16*)(ws + ((size_t)90 << 20));
    __bf16* vhT  = (__bf16*)(ws + ((size_t)106 << 20));
    __bf16* rkh  = (__bf16*)(ws + ((size_t)122 << 20));
    __bf16* avh  = (__bf16*)(ws + ((size_t)126 << 20));

    dim3 blk(256);
    // casts + weight transposes
    cast_bf16<<<4096, blk, 0, stream>>>(w, wbh);
    cast_bf16<<<1024, blk, 0, stream>>>(r, rbh);
    tcast<<<dim3(16, 16), blk, 0, stream>>>(Wq,  WqT,  DM, DM);
    tcast<<<dim3(32, 16), blk, 0, stream>>>(Wkv, WkvT, DM, 2 * DM);
    tcast<<<dim3(16, 16), blk, 0, stream>>>(Wr,  WrT,  DM, DM);
    tcast<<<dim3(16, 16), blk, 0, stream>>>(Wo,  WoT,  DM, DM);
    // projections (bf16 out)
    gemm_bf16<<<dim3(8, 8, 4), blk, 0, stream>>>(
        wbh + (size_t)MEM * DM, WqT, qh, QL, DM, DM,
        (long)KLN * DM, (long)QL * DM, 1);
    gemm_bf16<<<dim3(16, 16, 4), blk, 0, stream>>>(
        wbh, WkvT, kvh, KLN, 2 * DM, DM,
        (long)KLN * DM, (long)KLN * 2 * DM, 1);
    gemm_bf16<<<dim3(8, 16, 1), blk, 0, stream>>>(
        rbh, WrT, rkf, KLN, DM, DM, 0, 0, 1);
    // repacks
    cast_q<<<2048, blk, 0, stream>>>(qh, bwb, brb, qwh, qrh);
    cast_rk<<<1024, blk, 0, stream>>>(rkf, rkh);
    kv_split<<<dim3(32, 16, 4), blk, 0, stream>>>(kvh, kh, vhT);
    // attention
    attn_mfma<<<dim3(16, 16, 4), blk, 56320, stream>>>(qwh, qrh, kh, vhT, rkh, avh);
    // out projection (f32 out)
    gemm_bf16<<<dim3(8, 8, 4), blk, 0, stream>>>(
        avh, WoT, out, QL, DM, DM,
        (long)QL * DM, (long)QL * DM, 0);
}

// Round 4
// 421.981 us; speedup vs baseline: 6.9005x; 1.0592x over previous
//
#include <hip/hip_runtime.h>

// Problem constants (Transformer-XL attention)
constexpr int BSZ  = 4;
constexpr int NH   = 16;
constexpr int DH   = 64;
constexpr int QL   = 1024;
constexpr int KLN  = 2048;
constexpr int DM   = 1024;   // d_model = NH*DH
constexpr int MEM  = 1024;   // KLEN - QLEN

typedef __bf16 bf16x8  __attribute__((ext_vector_type(8)));
typedef __bf16 bf16x4t __attribute__((ext_vector_type(4)));
typedef float  f32x4   __attribute__((ext_vector_type(4)));

// async global->LDS, 16B per lane; LDS dst is wave-uniform base + lane*16
__device__ __forceinline__ void g2l16(__bf16* lds, const __bf16* g) {
    __builtin_amdgcn_global_load_lds(
        (const __attribute__((address_space(1))) unsigned int*)g,
        (__attribute__((address_space(3))) unsigned int*)lds, 16, 0, 0);
}

// ---------------------------------------------------------------------------
// cast w & r to bf16 in one launch. 8 elems/thread.
// w: 8M elems -> blocks [0,4096); r: 2M elems -> blocks [4096,5120)
// ---------------------------------------------------------------------------
__global__ __launch_bounds__(256)
void cast_wr(const float* __restrict__ w, const float* __restrict__ r,
             __bf16* __restrict__ wbh, __bf16* __restrict__ rbh)
{
    const int blk = blockIdx.x;
    const float* in;
    __bf16* out;
    size_t i;
    if (blk < 4096) { in = w; out = wbh; i = ((size_t)blk * 256 + threadIdx.x) * 8; }
    else { in = r; out = rbh; i = ((size_t)(blk - 4096) * 256 + threadIdx.x) * 8; }
    float4 a = *(const float4*)(in + i);
    float4 b = *(const float4*)(in + i + 4);
    bf16x8 y = {(__bf16)a.x, (__bf16)a.y, (__bf16)a.z, (__bf16)a.w,
                (__bf16)b.x, (__bf16)b.y, (__bf16)b.z, (__bf16)b.w};
    *(bf16x8*)(out + i) = y;
}

// ---------------------------------------------------------------------------
// transpose-cast all 4 weights: in f32 [1024][N] -> out bf16 [N][1024].
// z: 0 Wq, 1 Wr, 2 Wo (N=1024), 3 Wkv (N=2048). 64x64 tiles.
// ---------------------------------------------------------------------------
__global__ __launch_bounds__(256)
void tcast_all(const float* __restrict__ Wq, const float* __restrict__ Wr,
               const float* __restrict__ Wo, const float* __restrict__ Wkv,
               __bf16* __restrict__ WqT, __bf16* __restrict__ WrT,
               __bf16* __restrict__ WoT, __bf16* __restrict__ WkvT)
{
    const int z = blockIdx.z;
    const float* in;
    __bf16* out;
    int N;
    if (z == 0)      { in = Wq;  out = WqT;  N = 1024; }
    else if (z == 1) { in = Wr;  out = WrT;  N = 1024; }
    else if (z == 2) { in = Wo;  out = WoT;  N = 1024; }
    else             { in = Wkv; out = WkvT; N = 2048; }
    if (blockIdx.x * 64 >= N) return;
    __shared__ __bf16 t[64 * 72];
    const int n0 = blockIdx.x * 64, k0 = blockIdx.y * 64;
    const int row = threadIdx.x >> 2, seg = (threadIdx.x & 3) << 4;
    const float* src = in + (long)(k0 + row) * N + n0 + seg;
#pragma unroll
    for (int u = 0; u < 16; u += 4) {
        float4 x = *(const float4*)(src + u);
        t[(seg + u + 0) * 72 + row] = (__bf16)x.x;
        t[(seg + u + 1) * 72 + row] = (__bf16)x.y;
        t[(seg + u + 2) * 72 + row] = (__bf16)x.z;
        t[(seg + u + 3) * 72 + row] = (__bf16)x.w;
    }
    __syncthreads();
    __bf16* dst = out + (long)(n0 + row) * 1024 + k0 + seg;
    *(uint4*)(dst)     = *(const uint4*)(t + row * 72 + seg);
    *(uint4*)(dst + 8) = *(const uint4*)(t + row * 72 + seg + 8);
}

// ---------------------------------------------------------------------------
// bf16 MFMA GEMM: C = A[M,K] @ BT[N,K]^T.  Tile 128x128, BK=32, 4 waves.
// Fused epilogue kinds:
//   0: f32 row-major C (c0, batch stride sC)
//   2: q-repack -> qwh/qrh [b][hn][m][64] bf16, + biases bw/br
//   3: kv-repack -> kh [b][hn][m][64] (cols<1024) / vhT [b][hn][d][2048] (cols>=1024)
//   4: rk-repack -> rkh [hn][m][64]
// ---------------------------------------------------------------------------
__global__ __launch_bounds__(256, 2)
void gemm_bf16(const __bf16* __restrict__ A, const __bf16* __restrict__ BT,
               void* __restrict__ c0, void* __restrict__ c1,
               const float* __restrict__ bw, const float* __restrict__ br,
               int M, int N, int K, long sA, long sC, int kind)
{
    __shared__ __bf16 As[128 * 32];
    __shared__ __bf16 Bs[128 * 32];
    const int zz = blockIdx.z;
    A += (long)zz * sA;
    const int m0 = blockIdx.y * 128, n0 = blockIdx.x * 128;
    const int tid = threadIdx.x, w = tid >> 6, l = tid & 63;
    const int il = l & 15, quad = l >> 4;
    const int wm = (w >> 1) * 64, wn = (w & 1) * 64;
    const int lr = l >> 2, kc = (l & 3) ^ (lr & 3);

    const __bf16* ag = A  + (long)(m0 + w * 32 + lr) * K + kc * 8;
    const __bf16* bg = BT + (long)(n0 + w * 32 + lr) * K + kc * 8;
    __bf16* al0 = As + (w * 32) * 32;
    __bf16* al1 = As + (w * 32 + 16) * 32;
    __bf16* bl0 = Bs + (w * 32) * 32;
    __bf16* bl1 = Bs + (w * 32 + 16) * 32;

    f32x4 acc[4][4] = {};
    const int rsw = (il & 3);

    for (int k0 = 0; k0 < K; k0 += 32) {
        __syncthreads();
        g2l16(al0, ag + k0);
        g2l16(al1, ag + k0 + 16 * K);
        g2l16(bl0, bg + k0);
        g2l16(bl1, bg + k0 + 16 * K);
        __syncthreads();

        bf16x8 af[4], bf[4];
#pragma unroll
        for (int f = 0; f < 4; ++f) {
            af[f] = *(const bf16x8*)(As + (wm + f * 16 + il) * 32 + ((quad ^ rsw) << 3));
            bf[f] = *(const bf16x8*)(Bs + (wn + f * 16 + il) * 32 + ((quad ^ rsw) << 3));
        }
#pragma unroll
        for (int i = 0; i < 4; ++i)
#pragma unroll
            for (int j = 0; j < 4; ++j)
                acc[i][j] = __builtin_amdgcn_mfma_f32_16x16x32_bf16(
                    af[i], bf[j], acc[i][j], 0, 0, 0);
    }

    if (kind == 0) {
        float* C = (float*)c0 + (long)zz * sC;
#pragma unroll
        for (int i = 0; i < 4; ++i)
#pragma unroll
            for (int j = 0; j < 4; ++j) {
                float* cp = C + (long)(m0 + wm + i * 16 + quad * 4) * N
                              + n0 + wn + j * 16 + il;
#pragma unroll
                for (int r = 0; r < 4; ++r) cp[(long)r * N] = acc[i][j][r];
            }
    } else if (kind == 2) {
#pragma unroll
        for (int j = 0; j < 4; ++j) {
            const int col = n0 + wn + j * 16 + il;
            const int hn = col >> 6, d = col & 63;
            const float bwv = bw[col], brv = br[col];
            __bf16* q1 = (__bf16*)c0 + ((size_t)(zz * 16 + hn) * 1024) * 64 + d;
            __bf16* q2 = (__bf16*)c1 + ((size_t)(zz * 16 + hn) * 1024) * 64 + d;
#pragma unroll
            for (int i = 0; i < 4; ++i) {
                const int mb = m0 + wm + i * 16 + quad * 4;
#pragma unroll
                for (int r = 0; r < 4; ++r) {
                    float v = acc[i][j][r];
                    q1[(size_t)(mb + r) * 64] = (__bf16)(v + bwv);
                    q2[(size_t)(mb + r) * 64] = (__bf16)(v + brv);
                }
            }
        }
    } else if (kind == 3) {
        if (n0 + wn < 1024) {
#pragma unroll
            for (int j = 0; j < 4; ++j) {
                const int col = n0 + wn + j * 16 + il;
                const int hn = col >> 6, d = col & 63;
                __bf16* kp = (__bf16*)c0 + ((size_t)(zz * 16 + hn) * 2048) * 64 + d;
#pragma unroll
                for (int i = 0; i < 4; ++i) {
                    const int mb = m0 + wm + i * 16 + quad * 4;
#pragma unroll
                    for (int r = 0; r < 4; ++r)
                        kp[(size_t)(mb + r) * 64] = (__bf16)acc[i][j][r];
                }
            }
        } else {
#pragma unroll
            for (int j = 0; j < 4; ++j) {
                const int col = n0 + wn + j * 16 + il - 1024;
                const int hn = col >> 6, d = col & 63;
                __bf16* vp = (__bf16*)c1 + ((size_t)((zz * 16 + hn) * 64 + d)) * 2048;
#pragma unroll
                for (int i = 0; i < 4; ++i) {
                    const int mb = m0 + wm + i * 16 + quad * 4;
                    bf16x4t pk = {(__bf16)acc[i][j][0], (__bf16)acc[i][j][1],
                                  (__bf16)acc[i][j][2], (__bf16)acc[i][j][3]};
                    *(bf16x4t*)(vp + mb) = pk;
                }
            }
        }
    } else { // kind 4: rk
#pragma unroll
        for (int j = 0; j < 4; ++j) {
            const int col = n0 + wn + j * 16 + il;
            const int hn = col >> 6, d = col & 63;
            __bf16* rp = (__bf16*)c0 + ((size_t)hn * 2048) * 64 + d;
#pragma unroll
            for (int i = 0; i < 4; ++i) {
                const int mb = m0 + wm + i * 16 + quad * 4;
#pragma unroll
                for (int r = 0; r < 4; ++r)
                    rp[(size_t)(mb + r) * 64] = (__bf16)acc[i][j][r];
            }
        }
    }
}

// ---------------------------------------------------------------------------
// MFMA flash attention.  Grid (QL/64, NH, BSZ), 256 threads (4 waves).
// kt/vt/rkt: unpadded rows of 64 bf16, 8-chunk XOR swizzle, staged via
// global_load_lds.  Element offset of (row, chunk c) = row*64 + (c^(row&7))*8.
// Btilde: per-wave bt[i][u] stride 100 (b64 writes, u16 gather reads).
// P: per-wave pt[i][j] stride 88 (b64 writes, b128 reads).
// LDS: kt 8KB | vt 8KB | rkt 16KB | pt 11KB | bt 12.5KB = 56832 B.
// ---------------------------------------------------------------------------
__global__ __launch_bounds__(256, 2)
void attn_mfma(const __bf16* __restrict__ qwh, const __bf16* __restrict__ qrh,
               const __bf16* __restrict__ kh, const __bf16* __restrict__ vhT,
               const __bf16* __restrict__ rkh, __bf16* __restrict__ av)
{
    extern __shared__ __bf16 smem[];
    __bf16* kt  = smem;            // [64][64] xor-swizzled
    __bf16* vt  = smem + 4096;     // [64][64] xor
    __bf16* rkt = smem + 8192;     // [128][64] xor
    __bf16* pt  = smem + 16384;    // 4 x [16][88]
    __bf16* bt  = smem + 22016;    // 4 x [16][100]

    const int i0 = blockIdx.x * 64;
    const int n = blockIdx.y, b = blockIdx.z;
    const int tid = threadIdx.x;
    const int w = tid >> 6, l = tid & 63;
    const int il = l & 15, quad = l >> 4;
    const int iw0 = i0 + w * 16;
    const int i_gl = iw0 + il;

    __bf16* ptw = pt + w * (16 * 88);
    __bf16* btw = bt + w * (16 * 100);

    const size_t qoff = ((size_t)((b * 16 + n) * QL + iw0 + il)) * 64 + quad * 8;
    bf16x8 qwf0 = *(const bf16x8*)(qwh + qoff);
    bf16x8 qwf1 = *(const bf16x8*)(qwh + qoff + 32);
    bf16x8 qrf0 = *(const bf16x8*)(qrh + qoff);
    bf16x8 qrf1 = *(const bf16x8*)(qrh + qoff + 32);

    f32x4 O[4] = {};
    float m_i = -1e30f, l_i = 0.f;
    const float c = 0.125f * 1.44269504f;   // scale * log2(e)

    const int srow = l >> 3, scl = l & 7;   // staging: 8 rows x 8 chunks / wave
    const __bf16* kbase  = kh  + ((size_t)((b * 16 + n) * KLN)) * 64;
    const __bf16* vbase0 = vhT + ((size_t)((b * 16 + n) * 64)) * KLN;
    const __bf16* rbp    = rkh + ((size_t)(n * KLN)) * 64;
    const int ub = 48 - 16 * w;             // wave's base row inside rkt

    // frag-read chunk offsets (XOR key il&7, rows of all tiles are ≡ il mod 8)
    const int xk0 = ((quad) ^ (il & 7)) << 3;
    const int xk1 = ((quad + 4) ^ (il & 7)) << 3;

    const int ntiles = (i0 + 63 + MEM) / 64 + 1;

    for (int jt = 0; jt < ntiles; ++jt) {
        const int j0 = jt * 64;
        const int vu0 = j0 - i0 + 960;
        __syncthreads();
#pragma unroll
        for (int it = 0; it < 2; ++it) {    // K tile rows j
            const int row = w * 16 + it * 8 + srow;
            g2l16(kt + (w * 16 + it * 8) * 64,
                  kbase + ((size_t)(j0 + row)) * 64 + ((scl ^ (row & 7)) << 3));
        }
#pragma unroll
        for (int it = 0; it < 2; ++it) {    // V^T tile rows d
            const int row = w * 16 + it * 8 + srow;
            g2l16(vt + (w * 16 + it * 8) * 64,
                  vbase0 + (size_t)row * KLN + j0 + ((scl ^ (row & 7)) << 3));
        }
#pragma unroll
        for (int it = 0; it < 4; ++it) {    // rk band rows (clamp OOB=masked)
            const int row = w * 32 + it * 8 + srow;
            int vu = vu0 + row;
            vu = vu < 0 ? 0 : (vu > KLN - 1 ? KLN - 1 : vu);
            g2l16(rkt + (w * 32 + it * 8) * 64,
                  rbp + (size_t)vu * 64 + ((scl ^ (row & 7)) << 3));
        }
        __syncthreads();

        // ---- AC^T: S^T[j][i] = K·Qw
        f32x4 sf[4];
#pragma unroll
        for (int fr = 0; fr < 4; ++fr) {
            const __bf16* ka = kt + (fr * 16 + il) * 64;
            bf16x8 a0 = *(const bf16x8*)(ka + xk0);
            bf16x8 a1 = *(const bf16x8*)(ka + xk1);
            f32x4 acc = {};
            acc = __builtin_amdgcn_mfma_f32_16x16x32_bf16(a0, qwf0, acc, 0, 0, 0);
            acc = __builtin_amdgcn_mfma_f32_16x16x32_bf16(a1, qwf1, acc, 0, 0, 0);
            sf[fr] = acc;
        }
        // ---- Btilde^T = RK·Qr -> bt[i][u] (b64 stores)
#pragma unroll
        for (int uf = 0; uf < 5; ++uf) {
            const __bf16* ra = rkt + (ub + uf * 16 + il) * 64;
            bf16x8 a0 = *(const bf16x8*)(ra + xk0);
            bf16x8 a1 = *(const bf16x8*)(ra + xk1);
            f32x4 acc = {};
            acc = __builtin_amdgcn_mfma_f32_16x16x32_bf16(a0, qrf0, acc, 0, 0, 0);
            acc = __builtin_amdgcn_mfma_f32_16x16x32_bf16(a1, qrf1, acc, 0, 0, 0);
            bf16x4t bb = {(__bf16)acc[0], (__bf16)acc[1],
                          (__bf16)acc[2], (__bf16)acc[3]};
            *(bf16x4t*)(btw + il * 100 + uf * 16 + quad * 4) = bb;
        }

        // ---- gather shift (+ mask only on boundary tiles); tile max
        float sv[4][4];
        float tmax = -1e30f;
        if (j0 + 63 > i0 + MEM) {
#pragma unroll
            for (int fr = 0; fr < 4; ++fr)
#pragma unroll
                for (int r = 0; r < 4; ++r) {
                    const int jl_ = fr * 16 + quad * 4 + r;
                    float s = sf[fr][r] + (float)btw[il * 100 + (jl_ - il + 15)];
                    s = (j0 + jl_ > i_gl + MEM) ? -1e30f : s;
                    sv[fr][r] = s;
                    tmax = fmaxf(tmax, s);
                }
        } else {
#pragma unroll
            for (int fr = 0; fr < 4; ++fr)
#pragma unroll
                for (int r = 0; r < 4; ++r) {
                    const int jl_ = fr * 16 + quad * 4 + r;
                    float s = sf[fr][r] + (float)btw[il * 100 + (jl_ - il + 15)];
                    sv[fr][r] = s;
                    tmax = fmaxf(tmax, s);
                }
        }
        tmax = fmaxf(tmax, __shfl_xor(tmax, 16));
        tmax = fmaxf(tmax, __shfl_xor(tmax, 32));
        const float m_new = fmaxf(m_i, tmax);
        const float alpha = exp2f((m_i - m_new) * c);
        float psum = 0.f;
#pragma unroll
        for (int fr = 0; fr < 4; ++fr) {
            bf16x4t p4;
#pragma unroll
            for (int r = 0; r < 4; ++r) {
                float p = exp2f((sv[fr][r] - m_new) * c);
                psum += p;
                p4[r] = (__bf16)p;
            }
            *(bf16x4t*)(ptw + il * 88 + fr * 16 + quad * 4) = p4;
        }
        psum += __shfl_xor(psum, 16);
        psum += __shfl_xor(psum, 32);
        l_i = l_i * alpha + psum;
        m_i = m_new;
#pragma unroll
        for (int df = 0; df < 4; ++df) O[df] *= alpha;

        // ---- O^T += V^T · P
        bf16x8 p0 = *(const bf16x8*)(ptw + il * 88 + quad * 8);
        bf16x8 p1 = *(const bf16x8*)(ptw + il * 88 + 32 + quad * 8);
#pragma unroll
        for (int df = 0; df < 4; ++df) {
            const __bf16* va = vt + (df * 16 + il) * 64;
            bf16x8 a0 = *(const bf16x8*)(va + xk0);
            bf16x8 a1 = *(const bf16x8*)(va + xk1);
            O[df] = __builtin_amdgcn_mfma_f32_16x16x32_bf16(a0, p0, O[df], 0, 0, 0);
            O[df] = __builtin_amdgcn_mfma_f32_16x16x32_bf16(a1, p1, O[df], 0, 0, 0);
        }
    }

    const float inv = 1.0f / l_i;
    __bf16* ob = av + ((size_t)(b * QL + i_gl)) * DM + n * 64 + quad * 4;
#pragma unroll
    for (int df = 0; df < 4; ++df) {
        f32x4 o = O[df] * inv;
        bf16x4t y = {(__bf16)o[0], (__bf16)o[1], (__bf16)o[2], (__bf16)o[3]};
        *(bf16x4t*)(ob + df * 16) = y;
    }
}

// ---------------------------------------------------------------------------
// Workspace (MB offsets, 90 MB total):
//  0 wbh(16) | 16 rbh(4) | 20 WqT(2) | 22 WkvT(4) | 26 WrT(2) | 28 WoT(2)
//  30 qwh(8) | 38 qrh(8) | 46 kh(16) | 62 vhT(16) | 78 rkh(4) | 82 avh(8)
// ---------------------------------------------------------------------------
extern "C" void kernel_launch(void* const* d_in, const int* in_sizes, int n_in,
                              void* d_out, int out_size, void* d_ws, size_t ws_size,
                              hipStream_t stream)
{
    const float* w   = (const float*)d_in[0];
    const float* r   = (const float*)d_in[1];
    const float* bwb = (const float*)d_in[2];
    const float* brb = (const float*)d_in[3];
    const float* Wq  = (const float*)d_in[4];
    const float* Wkv = (const float*)d_in[5];
    const float* Wr  = (const float*)d_in[6];
    const float* Wo  = (const float*)d_in[7];
    float* out = (float*)d_out;

    char* ws = (char*)d_ws;
    __bf16* wbh  = (__bf16*)(ws);
    __bf16* rbh  = (__bf16*)(ws + ((size_t)16 << 20));
    __bf16* WqT  = (__bf16*)(ws + ((size_t)20 << 20));
    __bf16* WkvT = (__bf16*)(ws + ((size_t)22 << 20));
    __bf16* WrT  = (__bf16*)(ws + ((size_t)26 << 20));
    __bf16* WoT  = (__bf16*)(ws + ((size_t)28 << 20));
    __bf16* qwh  = (__bf16*)(ws + ((size_t)30 << 20));
    __bf16* qrh  = (__bf16*)(ws + ((size_t)38 << 20));
    __bf16* kh   = (__bf16*)(ws + ((size_t)46 << 20));
    __bf16* vhT  = (__bf16*)(ws + ((size_t)62 << 20));
    __bf16* rkh  = (__bf16*)(ws + ((size_t)78 << 20));
    __bf16* avh  = (__bf16*)(ws + ((size_t)82 << 20));

    dim3 blk(256);
    cast_wr<<<5120, blk, 0, stream>>>(w, r, wbh, rbh);
    tcast_all<<<dim3(32, 16, 4), blk, 0, stream>>>(Wq, Wr, Wo, Wkv,
                                                   WqT, WrT, WoT, WkvT);
    // q projection -> qwh/qrh (biases fused)
    gemm_bf16<<<dim3(8, 8, 4), blk, 0, stream>>>(
        wbh + (size_t)MEM * DM, WqT, qwh, qrh, bwb, brb,
        QL, DM, DM, (long)KLN * DM, 0, 2);
    // kv projection -> kh / vhT
    gemm_bf16<<<dim3(16, 16, 4), blk, 0, stream>>>(
        wbh, WkvT, kh, vhT, bwb, brb,
        KLN, 2 * DM, DM, (long)KLN * DM, 0, 3);
    // rk projection -> rkh
    gemm_bf16<<<dim3(8, 16, 1), blk, 0, stream>>>(
        rbh, WrT, rkh, rkh, bwb, brb,
        KLN, DM, DM, 0, 0, 4);
    // attention
    attn_mfma<<<dim3(16, 16, 4), blk, 56832, stream>>>(qwh, qrh, kh, vhT, rkh, avh);
    // out projection (f32)
    gemm_bf16<<<dim3(8, 8, 4), blk, 0, stream>>>(
        avh, WoT, out, out, bwb, brb,
        QL, DM, DM, (long)QL * DM, (long)QL * DM, 0);
}

// Round 5
// 416.488 us; speedup vs baseline: 6.9915x; 1.0132x over previous
//
#include <hip/hip_runtime.h>

// Problem constants (Transformer-XL attention)
constexpr int BSZ  = 4;
constexpr int NH   = 16;
constexpr int DH   = 64;
constexpr int QL   = 1024;
constexpr int KLN  = 2048;
constexpr int DM   = 1024;   // d_model = NH*DH
constexpr int MEM  = 1024;   // KLEN - QLEN

typedef __bf16 bf16x8  __attribute__((ext_vector_type(8)));
typedef __bf16 bf16x4t __attribute__((ext_vector_type(4)));
typedef float  f32x4   __attribute__((ext_vector_type(4)));

// async global->LDS, 16B per lane; LDS dst is wave-uniform base + lane*16
__device__ __forceinline__ void g2l16(__bf16* lds, const __bf16* g) {
    __builtin_amdgcn_global_load_lds(
        (const __attribute__((address_space(1))) unsigned int*)g,
        (__attribute__((address_space(3))) unsigned int*)lds, 16, 0, 0);
}

// ---------------------------------------------------------------------------
// cast w & r to bf16 in one launch. 8 elems/thread.
// ---------------------------------------------------------------------------
__global__ __launch_bounds__(256)
void cast_wr(const float* __restrict__ w, const float* __restrict__ r,
             __bf16* __restrict__ wbh, __bf16* __restrict__ rbh)
{
    const int blk = blockIdx.x;
    const float* in;
    __bf16* out;
    size_t i;
    if (blk < 4096) { in = w; out = wbh; i = ((size_t)blk * 256 + threadIdx.x) * 8; }
    else { in = r; out = rbh; i = ((size_t)(blk - 4096) * 256 + threadIdx.x) * 8; }
    float4 a = *(const float4*)(in + i);
    float4 b = *(const float4*)(in + i + 4);
    bf16x8 y = {(__bf16)a.x, (__bf16)a.y, (__bf16)a.z, (__bf16)a.w,
                (__bf16)b.x, (__bf16)b.y, (__bf16)b.z, (__bf16)b.w};
    *(bf16x8*)(out + i) = y;
}

// ---------------------------------------------------------------------------
// transpose-cast all 4 weights: in f32 [1024][N] -> out bf16 [N][1024].
// ---------------------------------------------------------------------------
__global__ __launch_bounds__(256)
void tcast_all(const float* __restrict__ Wq, const float* __restrict__ Wr,
               const float* __restrict__ Wo, const float* __restrict__ Wkv,
               __bf16* __restrict__ WqT, __bf16* __restrict__ WrT,
               __bf16* __restrict__ WoT, __bf16* __restrict__ WkvT)
{
    const int z = blockIdx.z;
    const float* in;
    __bf16* out;
    int N;
    if (z == 0)      { in = Wq;  out = WqT;  N = 1024; }
    else if (z == 1) { in = Wr;  out = WrT;  N = 1024; }
    else if (z == 2) { in = Wo;  out = WoT;  N = 1024; }
    else             { in = Wkv; out = WkvT; N = 2048; }
    if (blockIdx.x * 64 >= N) return;
    __shared__ __bf16 t[64 * 72];
    const int n0 = blockIdx.x * 64, k0 = blockIdx.y * 64;
    const int row = threadIdx.x >> 2, seg = (threadIdx.x & 3) << 4;
    const float* src = in + (long)(k0 + row) * N + n0 + seg;
#pragma unroll
    for (int u = 0; u < 16; u += 4) {
        float4 x = *(const float4*)(src + u);
        t[(seg + u + 0) * 72 + row] = (__bf16)x.x;
        t[(seg + u + 1) * 72 + row] = (__bf16)x.y;
        t[(seg + u + 2) * 72 + row] = (__bf16)x.z;
        t[(seg + u + 3) * 72 + row] = (__bf16)x.w;
    }
    __syncthreads();
    __bf16* dst = out + (long)(n0 + row) * 1024 + k0 + seg;
    *(uint4*)(dst)     = *(const uint4*)(t + row * 72 + seg);
    *(uint4*)(dst + 8) = *(const uint4*)(t + row * 72 + seg + 8);
}

// ---------------------------------------------------------------------------
// bf16 MFMA GEMM: C = A[M,K] @ BT[N,K]^T.  Tile 128x128, BK=32, 4 waves.
// Epilogue kinds: 0 f32 C | 2 q-repack+bias | 3 kv-repack | 4 rk-repack
// ---------------------------------------------------------------------------
__global__ __launch_bounds__(256, 2)
void gemm_bf16(const __bf16* __restrict__ A, const __bf16* __restrict__ BT,
               void* __restrict__ c0, void* __restrict__ c1,
               const float* __restrict__ bw, const float* __restrict__ br,
               int M, int N, int K, long sA, long sC, int kind)
{
    __shared__ __bf16 As[128 * 32];
    __shared__ __bf16 Bs[128 * 32];
    const int zz = blockIdx.z;
    A += (long)zz * sA;
    const int m0 = blockIdx.y * 128, n0 = blockIdx.x * 128;
    const int tid = threadIdx.x, w = tid >> 6, l = tid & 63;
    const int il = l & 15, quad = l >> 4;
    const int wm = (w >> 1) * 64, wn = (w & 1) * 64;
    const int lr = l >> 2, kc = (l & 3) ^ (lr & 3);

    const __bf16* ag = A  + (long)(m0 + w * 32 + lr) * K + kc * 8;
    const __bf16* bg = BT + (long)(n0 + w * 32 + lr) * K + kc * 8;
    __bf16* al0 = As + (w * 32) * 32;
    __bf16* al1 = As + (w * 32 + 16) * 32;
    __bf16* bl0 = Bs + (w * 32) * 32;
    __bf16* bl1 = Bs + (w * 32 + 16) * 32;

    f32x4 acc[4][4] = {};
    const int rsw = (il & 3);

    for (int k0 = 0; k0 < K; k0 += 32) {
        __syncthreads();
        g2l16(al0, ag + k0);
        g2l16(al1, ag + k0 + 16 * K);
        g2l16(bl0, bg + k0);
        g2l16(bl1, bg + k0 + 16 * K);
        __syncthreads();

        bf16x8 af[4], bf[4];
#pragma unroll
        for (int f = 0; f < 4; ++f) {
            af[f] = *(const bf16x8*)(As + (wm + f * 16 + il) * 32 + ((quad ^ rsw) << 3));
            bf[f] = *(const bf16x8*)(Bs + (wn + f * 16 + il) * 32 + ((quad ^ rsw) << 3));
        }
#pragma unroll
        for (int i = 0; i < 4; ++i)
#pragma unroll
            for (int j = 0; j < 4; ++j)
                acc[i][j] = __builtin_amdgcn_mfma_f32_16x16x32_bf16(
                    af[i], bf[j], acc[i][j], 0, 0, 0);
    }

    if (kind == 0) {
        float* C = (float*)c0 + (long)zz * sC;
#pragma unroll
        for (int i = 0; i < 4; ++i)
#pragma unroll
            for (int j = 0; j < 4; ++j) {
                float* cp = C + (long)(m0 + wm + i * 16 + quad * 4) * N
                              + n0 + wn + j * 16 + il;
#pragma unroll
                for (int r = 0; r < 4; ++r) cp[(long)r * N] = acc[i][j][r];
            }
    } else if (kind == 2) {
#pragma unroll
        for (int j = 0; j < 4; ++j) {
            const int col = n0 + wn + j * 16 + il;
            const int hn = col >> 6, d = col & 63;
            const float bwv = bw[col], brv = br[col];
            __bf16* q1 = (__bf16*)c0 + ((size_t)(zz * 16 + hn) * 1024) * 64 + d;
            __bf16* q2 = (__bf16*)c1 + ((size_t)(zz * 16 + hn) * 1024) * 64 + d;
#pragma unroll
            for (int i = 0; i < 4; ++i) {
                const int mb = m0 + wm + i * 16 + quad * 4;
#pragma unroll
                for (int r = 0; r < 4; ++r) {
                    float v = acc[i][j][r];
                    q1[(size_t)(mb + r) * 64] = (__bf16)(v + bwv);
                    q2[(size_t)(mb + r) * 64] = (__bf16)(v + brv);
                }
            }
        }
    } else if (kind == 3) {
        if (n0 + wn < 1024) {
#pragma unroll
            for (int j = 0; j < 4; ++j) {
                const int col = n0 + wn + j * 16 + il;
                const int hn = col >> 6, d = col & 63;
                __bf16* kp = (__bf16*)c0 + ((size_t)(zz * 16 + hn) * 2048) * 64 + d;
#pragma unroll
                for (int i = 0; i < 4; ++i) {
                    const int mb = m0 + wm + i * 16 + quad * 4;
#pragma unroll
                    for (int r = 0; r < 4; ++r)
                        kp[(size_t)(mb + r) * 64] = (__bf16)acc[i][j][r];
                }
            }
        } else {
#pragma unroll
            for (int j = 0; j < 4; ++j) {
                const int col = n0 + wn + j * 16 + il - 1024;
                const int hn = col >> 6, d = col & 63;
                __bf16* vp = (__bf16*)c1 + ((size_t)((zz * 16 + hn) * 64 + d)) * 2048;
#pragma unroll
                for (int i = 0; i < 4; ++i) {
                    const int mb = m0 + wm + i * 16 + quad * 4;
                    bf16x4t pk = {(__bf16)acc[i][j][0], (__bf16)acc[i][j][1],
                                  (__bf16)acc[i][j][2], (__bf16)acc[i][j][3]};
                    *(bf16x4t*)(vp + mb) = pk;
                }
            }
        }
    } else { // kind 4: rk
#pragma unroll
        for (int j = 0; j < 4; ++j) {
            const int col = n0 + wn + j * 16 + il;
            const int hn = col >> 6, d = col & 63;
            __bf16* rp = (__bf16*)c0 + ((size_t)hn * 2048) * 64 + d;
#pragma unroll
            for (int i = 0; i < 4; ++i) {
                const int mb = m0 + wm + i * 16 + quad * 4;
#pragma unroll
                for (int r = 0; r < 4; ++r)
                    rp[(size_t)(mb + r) * 64] = (__bf16)acc[i][j][r];
            }
        }
    }
}

// ---------------------------------------------------------------------------
// MFMA flash attention.  Grid (QL/64, NH, BSZ), 256 threads (4 waves).
// R5: LDS 45KB -> 3 blocks/CU.  rkt is a 128-row circular band (slide=64,
// physical row = (logical + 64*jt) & 127; only 64 new rows staged per tile).
// Per-wave scratch region unions Btilde tile [16][104] (written by BD-MFMA,
// consumed by the shift gather) with the P tile [16][88] (written after the
// gather -> data dependency orders the reuse).  i-block swizzle pairs
// short/long blocks for per-CU load balance.
// LDS: kt 8KB | vt 8KB | rkt 16KB | scratch 4x3328B = 46080 B.
// ---------------------------------------------------------------------------
__global__ __launch_bounds__(256, 3)
void attn_mfma(const __bf16* __restrict__ qwh, const __bf16* __restrict__ qrh,
               const __bf16* __restrict__ kh, const __bf16* __restrict__ vhT,
               const __bf16* __restrict__ rkh, __bf16* __restrict__ av)
{
    extern __shared__ __bf16 smem[];
    __bf16* kt  = smem;            // [64][64] xor-swizzled
    __bf16* vt  = smem + 4096;     // [64][64] xor
    __bf16* rkt = smem + 8192;     // [128][64] xor, circular
    __bf16* sc  = smem + 16384;    // 4 x 1664: per-wave bt[16][104] / pt[16][88]

    // load-balance swizzle: pair i-blocks (0,15),(1,14),... so consecutive
    // block pairs have ~equal total j-tiles
    const int bx = blockIdx.x;
    const int ib = (bx & 1) ? (15 - (bx >> 1)) : (bx >> 1);
    const int i0 = ib * 64;
    const int n = blockIdx.y, b = blockIdx.z;
    const int tid = threadIdx.x;
    const int w = tid >> 6, l = tid & 63;
    const int il = l & 15, quad = l >> 4;
    const int iw0 = i0 + w * 16;
    const int i_gl = iw0 + il;

    __bf16* btw = sc + w * 1664;   // stride 104
    __bf16* ptw = sc + w * 1664;   // stride 88 (union, see header comment)

    const size_t qoff = ((size_t)((b * 16 + n) * QL + iw0 + il)) * 64 + quad * 8;
    bf16x8 qwf0 = *(const bf16x8*)(qwh + qoff);
    bf16x8 qwf1 = *(const bf16x8*)(qwh + qoff + 32);
    bf16x8 qrf0 = *(const bf16x8*)(qrh + qoff);
    bf16x8 qrf1 = *(const bf16x8*)(qrh + qoff + 32);

    f32x4 O[4] = {};
    float m_i = -1e30f, l_i = 0.f;
    const float c = 0.125f * 1.44269504f;   // scale * log2(e)

    const int srow = l >> 3, scl = l & 7;   // staging: 8 rows x 8 chunks / wave
    const __bf16* kbase  = kh  + ((size_t)((b * 16 + n) * KLN)) * 64;
    const __bf16* vbase0 = vhT + ((size_t)((b * 16 + n) * 64)) * KLN;
    const __bf16* rbp    = rkh + ((size_t)(n * KLN)) * 64;
    const int ub = 48 - 16 * w;             // wave's base logical row in rkt

    const int xk0 = ((quad) ^ (il & 7)) << 3;
    const int xk1 = ((quad + 4) ^ (il & 7)) << 3;

    const int ntiles = (i0 + 63 + MEM) / 64 + 1;

    for (int jt = 0; jt < ntiles; ++jt) {
        const int j0 = jt * 64;
        const int vu0 = j0 - i0 + 960;       // rk row of logical rkt row 0
        const int rot = (jt << 6) & 127;     // circular offset
        __syncthreads();
#pragma unroll
        for (int it = 0; it < 2; ++it) {    // K tile rows j
            const int row = w * 16 + it * 8 + srow;
            g2l16(kt + (w * 16 + it * 8) * 64,
                  kbase + ((size_t)(j0 + row)) * 64 + ((scl ^ (row & 7)) << 3));
        }
#pragma unroll
        for (int it = 0; it < 2; ++it) {    // V^T tile rows d
            const int row = w * 16 + it * 8 + srow;
            g2l16(vt + (w * 16 + it * 8) * 64,
                  vbase0 + (size_t)row * KLN + j0 + ((scl ^ (row & 7)) << 3));
        }
        if (jt == 0) {                       // rk band: full 128 rows
#pragma unroll
            for (int it = 0; it < 4; ++it) {
                const int row = w * 32 + it * 8 + srow;
                int vu = vu0 + row;
                vu = vu < 0 ? 0 : (vu > KLN - 1 ? KLN - 1 : vu);
                g2l16(rkt + (w * 32 + it * 8) * 64,
                      rbp + (size_t)vu * 64 + ((scl ^ (row & 7)) << 3));
            }
        } else {                             // only 64 new rows (logical 64..127)
#pragma unroll
            for (int it = 0; it < 2; ++it) {
                const int row = 64 + w * 16 + it * 8 + srow;  // logical
                int vu = vu0 + row;
                vu = vu < 0 ? 0 : (vu > KLN - 1 ? KLN - 1 : vu);
                const int prow = (64 + w * 16 + it * 8 + rot) & 127;  // physical base
                g2l16(rkt + prow * 64,
                      rbp + (size_t)vu * 64 + ((scl ^ (row & 7)) << 3));
            }
        }
        __syncthreads();

        // ---- AC^T: S^T[j][i] = K·Qw
        f32x4 sf[4];
#pragma unroll
        for (int fr = 0; fr < 4; ++fr) {
            const __bf16* ka = kt + (fr * 16 + il) * 64;
            bf16x8 a0 = *(const bf16x8*)(ka + xk0);
            bf16x8 a1 = *(const bf16x8*)(ka + xk1);
            f32x4 acc = {};
            acc = __builtin_amdgcn_mfma_f32_16x16x32_bf16(a0, qwf0, acc, 0, 0, 0);
            acc = __builtin_amdgcn_mfma_f32_16x16x32_bf16(a1, qwf1, acc, 0, 0, 0);
            sf[fr] = acc;
        }
        // ---- Btilde^T = RK·Qr -> bt[i][u] (b64 stores), circular row index
#pragma unroll
        for (int uf = 0; uf < 5; ++uf) {
            const int prow = ((ub + uf * 16 + il) + rot) & 127;
            const __bf16* ra = rkt + prow * 64;
            bf16x8 a0 = *(const bf16x8*)(ra + xk0);
            bf16x8 a1 = *(const bf16x8*)(ra + xk1);
            f32x4 acc = {};
            acc = __builtin_amdgcn_mfma_f32_16x16x32_bf16(a0, qrf0, acc, 0, 0, 0);
            acc = __builtin_amdgcn_mfma_f32_16x16x32_bf16(a1, qrf1, acc, 0, 0, 0);
            bf16x4t bb = {(__bf16)acc[0], (__bf16)acc[1],
                          (__bf16)acc[2], (__bf16)acc[3]};
            *(bf16x4t*)(btw + il * 104 + uf * 16 + quad * 4) = bb;
        }

        // ---- gather shift (+ mask only on boundary tiles); tile max
        float sv[4][4];
        float tmax = -1e30f;
        if (j0 + 63 > i0 + MEM) {
#pragma unroll
            for (int fr = 0; fr < 4; ++fr)
#pragma unroll
                for (int r = 0; r < 4; ++r) {
                    const int jl_ = fr * 16 + quad * 4 + r;
                    float s = sf[fr][r] + (float)btw[il * 104 + (jl_ - il + 15)];
                    s = (j0 + jl_ > i_gl + MEM) ? -1e30f : s;
                    sv[fr][r] = s;
                    tmax = fmaxf(tmax, s);
                }
        } else {
#pragma unroll
            for (int fr = 0; fr < 4; ++fr)
#pragma unroll
                for (int r = 0; r < 4; ++r) {
                    const int jl_ = fr * 16 + quad * 4 + r;
                    float s = sf[fr][r] + (float)btw[il * 104 + (jl_ - il + 15)];
                    sv[fr][r] = s;
                    tmax = fmaxf(tmax, s);
                }
        }
        tmax = fmaxf(tmax, __shfl_xor(tmax, 16));
        tmax = fmaxf(tmax, __shfl_xor(tmax, 32));
        const float m_new = fmaxf(m_i, tmax);
        const float alpha = exp2f((m_i - m_new) * c);
        float psum = 0.f;
#pragma unroll
        for (int fr = 0; fr < 4; ++fr) {
            bf16x4t p4;
#pragma unroll
            for (int r = 0; r < 4; ++r) {
                float p = exp2f((sv[fr][r] - m_new) * c);
                psum += p;
                p4[r] = (__bf16)p;
            }
            // overwrites the bt region: safe, p depends on the bt gather
            *(bf16x4t*)(ptw + il * 88 + fr * 16 + quad * 4) = p4;
        }
        psum += __shfl_xor(psum, 16);
        psum += __shfl_xor(psum, 32);
        l_i = l_i * alpha + psum;
        m_i = m_new;
#pragma unroll
        for (int df = 0; df < 4; ++df) O[df] *= alpha;

        // ---- O^T += V^T · P
        bf16x8 p0 = *(const bf16x8*)(ptw + il * 88 + quad * 8);
        bf16x8 p1 = *(const bf16x8*)(ptw + il * 88 + 32 + quad * 8);
#pragma unroll
        for (int df = 0; df < 4; ++df) {
            const __bf16* va = vt + (df * 16 + il) * 64;
            bf16x8 a0 = *(const bf16x8*)(va + xk0);
            bf16x8 a1 = *(const bf16x8*)(va + xk1);
            O[df] = __builtin_amdgcn_mfma_f32_16x16x32_bf16(a0, p0, O[df], 0, 0, 0);
            O[df] = __builtin_amdgcn_mfma_f32_16x16x32_bf16(a1, p1, O[df], 0, 0, 0);
        }
    }

    const float inv = 1.0f / l_i;
    __bf16* ob = av + ((size_t)(b * QL + i_gl)) * DM + n * 64 + quad * 4;
#pragma unroll
    for (int df = 0; df < 4; ++df) {
        f32x4 o = O[df] * inv;
        bf16x4t y = {(__bf16)o[0], (__bf16)o[1], (__bf16)o[2], (__bf16)o[3]};
        *(bf16x4t*)(ob + df * 16) = y;
    }
}

// ---------------------------------------------------------------------------
// Workspace (MB offsets, 90 MB total):
//  0 wbh(16) | 16 rbh(4) | 20 WqT(2) | 22 WkvT(4) | 26 WrT(2) | 28 WoT(2)
//  30 qwh(8) | 38 qrh(8) | 46 kh(16) | 62 vhT(16) | 78 rkh(4) | 82 avh(8)
// ---------------------------------------------------------------------------
extern "C" void kernel_launch(void* const* d_in, const int* in_sizes, int n_in,
                              void* d_out, int out_size, void* d_ws, size_t ws_size,
                              hipStream_t stream)
{
    const float* w   = (const float*)d_in[0];
    const float* r   = (const float*)d_in[1];
    const float* bwb = (const float*)d_in[2];
    const float* brb = (const float*)d_in[3];
    const float* Wq  = (const float*)d_in[4];
    const float* Wkv = (const float*)d_in[5];
    const float* Wr  = (const float*)d_in[6];
    const float* Wo  = (const float*)d_in[7];
    float* out = (float*)d_out;

    char* ws = (char*)d_ws;
    __bf16* wbh  = (__bf16*)(ws);
    __bf16* rbh  = (__bf16*)(ws + ((size_t)16 << 20));
    __bf16* WqT  = (__bf16*)(ws + ((size_t)20 << 20));
    __bf16* WkvT = (__bf16*)(ws + ((size_t)22 << 20));
    __bf16* WrT  = (__bf16*)(ws + ((size_t)26 << 20));
    __bf16* WoT  = (__bf16*)(ws + ((size_t)28 << 20));
    __bf16* qwh  = (__bf16*)(ws + ((size_t)30 << 20));
    __bf16* qrh  = (__bf16*)(ws + ((size_t)38 << 20));
    __bf16* kh   = (__bf16*)(ws + ((size_t)46 << 20));
    __bf16* vhT  = (__bf16*)(ws + ((size_t)62 << 20));
    __bf16* rkh  = (__bf16*)(ws + ((size_t)78 << 20));
    __bf16* avh  = (__bf16*)(ws + ((size_t)82 << 20));

    dim3 blk(256);
    cast_wr<<<5120, blk, 0, stream>>>(w, r, wbh, rbh);
    tcast_all<<<dim3(32, 16, 4), blk, 0, stream>>>(Wq, Wr, Wo, Wkv,
                                                   WqT, WrT, WoT, WkvT);
    // q projection -> qwh/qrh (biases fused)
    gemm_bf16<<<dim3(8, 8, 4), blk, 0, stream>>>(
        wbh + (size_t)MEM * DM, WqT, qwh, qrh, bwb, brb,
        QL, DM, DM, (long)KLN * DM, 0, 2);
    // kv projection -> kh / vhT
    gemm_bf16<<<dim3(16, 16, 4), blk, 0, stream>>>(
        wbh, WkvT, kh, vhT, bwb, brb,
        KLN, 2 * DM, DM, (long)KLN * DM, 0, 3);
    // rk projection -> rkh
    gemm_bf16<<<dim3(8, 16, 1), blk, 0, stream>>>(
        rbh, WrT, rkh, rkh, bwb, brb,
        KLN, DM, DM, 0, 0, 4);
    // attention
    attn_mfma<<<dim3(16, 16, 4), blk, 46080, stream>>>(qwh, qrh, kh, vhT, rkh, avh);
    // out projection (f32)
    gemm_bf16<<<dim3(8, 8, 4), blk, 0, stream>>>(
        avh, WoT, out, out, bwb, brb,
        QL, DM, DM, (long)QL * DM, (long)QL * DM, 0);
}

// Round 6
// 407.510 us; speedup vs baseline: 7.1456x; 1.0220x over previous
//
#include <hip/hip_runtime.h>

// Problem constants (Transformer-XL attention)
constexpr int BSZ  = 4;
constexpr int NH   = 16;
constexpr int DH   = 64;
constexpr int QL   = 1024;
constexpr int KLN  = 2048;
constexpr int DM   = 1024;   // d_model = NH*DH
constexpr int MEM  = 1024;   // KLEN - QLEN

typedef __bf16 bf16x8  __attribute__((ext_vector_type(8)));
typedef __bf16 bf16x4t __attribute__((ext_vector_type(4)));
typedef float  f32x4   __attribute__((ext_vector_type(4)));

// async global->LDS, 16B per lane; LDS dst is wave-uniform base + lane*16
__device__ __forceinline__ void g2l16(__bf16* lds, const __bf16* g) {
    __builtin_amdgcn_global_load_lds(
        (const __attribute__((address_space(1))) unsigned int*)g,
        (__attribute__((address_space(3))) unsigned int*)lds, 16, 0, 0);
}

// ---------------------------------------------------------------------------
// cast w & r to bf16 in one launch. 8 elems/thread.
// ---------------------------------------------------------------------------
__global__ __launch_bounds__(256)
void cast_wr(const float* __restrict__ w, const float* __restrict__ r,
             __bf16* __restrict__ wbh, __bf16* __restrict__ rbh)
{
    const int blk = blockIdx.x;
    const float* in;
    __bf16* out;
    size_t i;
    if (blk < 4096) { in = w; out = wbh; i = ((size_t)blk * 256 + threadIdx.x) * 8; }
    else { in = r; out = rbh; i = ((size_t)(blk - 4096) * 256 + threadIdx.x) * 8; }
    float4 a = *(const float4*)(in + i);
    float4 b = *(const float4*)(in + i + 4);
    bf16x8 y = {(__bf16)a.x, (__bf16)a.y, (__bf16)a.z, (__bf16)a.w,
                (__bf16)b.x, (__bf16)b.y, (__bf16)b.z, (__bf16)b.w};
    *(bf16x8*)(out + i) = y;
}

// ---------------------------------------------------------------------------
// transpose-cast all 4 weights: in f32 [1024][N] -> out bf16 [N][1024].
// ---------------------------------------------------------------------------
__global__ __launch_bounds__(256)
void tcast_all(const float* __restrict__ Wq, const float* __restrict__ Wr,
               const float* __restrict__ Wo, const float* __restrict__ Wkv,
               __bf16* __restrict__ WqT, __bf16* __restrict__ WrT,
               __bf16* __restrict__ WoT, __bf16* __restrict__ WkvT)
{
    const int z = blockIdx.z;
    const float* in;
    __bf16* out;
    int N;
    if (z == 0)      { in = Wq;  out = WqT;  N = 1024; }
    else if (z == 1) { in = Wr;  out = WrT;  N = 1024; }
    else if (z == 2) { in = Wo;  out = WoT;  N = 1024; }
    else             { in = Wkv; out = WkvT; N = 2048; }
    if (blockIdx.x * 64 >= N) return;
    __shared__ __bf16 t[64 * 72];
    const int n0 = blockIdx.x * 64, k0 = blockIdx.y * 64;
    const int row = threadIdx.x >> 2, seg = (threadIdx.x & 3) << 4;
    const float* src = in + (long)(k0 + row) * N + n0 + seg;
#pragma unroll
    for (int u = 0; u < 16; u += 4) {
        float4 x = *(const float4*)(src + u);
        t[(seg + u + 0) * 72 + row] = (__bf16)x.x;
        t[(seg + u + 1) * 72 + row] = (__bf16)x.y;
        t[(seg + u + 2) * 72 + row] = (__bf16)x.z;
        t[(seg + u + 3) * 72 + row] = (__bf16)x.w;
    }
    __syncthreads();
    __bf16* dst = out + (long)(n0 + row) * 1024 + k0 + seg;
    *(uint4*)(dst)     = *(const uint4*)(t + row * 72 + seg);
    *(uint4*)(dst + 8) = *(const uint4*)(t + row * 72 + seg + 8);
}

// ---------------------------------------------------------------------------
// bf16 MFMA GEMM: C = A[M,K] @ BT[N,K]^T.  Tile 128x128, BK=32, 4 waves.
// Epilogue kinds: 0 f32 C | 2 q-repack+bias | 3 kv-repack | 4 rk-repack
// ---------------------------------------------------------------------------
__global__ __launch_bounds__(256, 2)
void gemm_bf16(const __bf16* __restrict__ A, const __bf16* __restrict__ BT,
               void* __restrict__ c0, void* __restrict__ c1,
               const float* __restrict__ bw, const float* __restrict__ br,
               int M, int N, int K, long sA, long sC, int kind)
{
    __shared__ __bf16 As[128 * 32];
    __shared__ __bf16 Bs[128 * 32];
    const int zz = blockIdx.z;
    A += (long)zz * sA;
    const int m0 = blockIdx.y * 128, n0 = blockIdx.x * 128;
    const int tid = threadIdx.x, w = tid >> 6, l = tid & 63;
    const int il = l & 15, quad = l >> 4;
    const int wm = (w >> 1) * 64, wn = (w & 1) * 64;
    const int lr = l >> 2, kc = (l & 3) ^ (lr & 3);

    const __bf16* ag = A  + (long)(m0 + w * 32 + lr) * K + kc * 8;
    const __bf16* bg = BT + (long)(n0 + w * 32 + lr) * K + kc * 8;
    __bf16* al0 = As + (w * 32) * 32;
    __bf16* al1 = As + (w * 32 + 16) * 32;
    __bf16* bl0 = Bs + (w * 32) * 32;
    __bf16* bl1 = Bs + (w * 32 + 16) * 32;

    f32x4 acc[4][4] = {};
    const int rsw = (il & 3);

    for (int k0 = 0; k0 < K; k0 += 32) {
        __syncthreads();
        g2l16(al0, ag + k0);
        g2l16(al1, ag + k0 + 16 * K);
        g2l16(bl0, bg + k0);
        g2l16(bl1, bg + k0 + 16 * K);
        __syncthreads();

        bf16x8 af[4], bf[4];
#pragma unroll
        for (int f = 0; f < 4; ++f) {
            af[f] = *(const bf16x8*)(As + (wm + f * 16 + il) * 32 + ((quad ^ rsw) << 3));
            bf[f] = *(const bf16x8*)(Bs + (wn + f * 16 + il) * 32 + ((quad ^ rsw) << 3));
        }
#pragma unroll
        for (int i = 0; i < 4; ++i)
#pragma unroll
            for (int j = 0; j < 4; ++j)
                acc[i][j] = __builtin_amdgcn_mfma_f32_16x16x32_bf16(
                    af[i], bf[j], acc[i][j], 0, 0, 0);
    }

    if (kind == 0) {
        float* C = (float*)c0 + (long)zz * sC;
#pragma unroll
        for (int i = 0; i < 4; ++i)
#pragma unroll
            for (int j = 0; j < 4; ++j) {
                float* cp = C + (long)(m0 + wm + i * 16 + quad * 4) * N
                              + n0 + wn + j * 16 + il;
#pragma unroll
                for (int r = 0; r < 4; ++r) cp[(long)r * N] = acc[i][j][r];
            }
    } else if (kind == 2) {
#pragma unroll
        for (int j = 0; j < 4; ++j) {
            const int col = n0 + wn + j * 16 + il;
            const int hn = col >> 6, d = col & 63;
            const float bwv = bw[col], brv = br[col];
            __bf16* q1 = (__bf16*)c0 + ((size_t)(zz * 16 + hn) * 1024) * 64 + d;
            __bf16* q2 = (__bf16*)c1 + ((size_t)(zz * 16 + hn) * 1024) * 64 + d;
#pragma unroll
            for (int i = 0; i < 4; ++i) {
                const int mb = m0 + wm + i * 16 + quad * 4;
#pragma unroll
                for (int r = 0; r < 4; ++r) {
                    float v = acc[i][j][r];
                    q1[(size_t)(mb + r) * 64] = (__bf16)(v + bwv);
                    q2[(size_t)(mb + r) * 64] = (__bf16)(v + brv);
                }
            }
        }
    } else if (kind == 3) {
        if (n0 + wn < 1024) {
#pragma unroll
            for (int j = 0; j < 4; ++j) {
                const int col = n0 + wn + j * 16 + il;
                const int hn = col >> 6, d = col & 63;
                __bf16* kp = (__bf16*)c0 + ((size_t)(zz * 16 + hn) * 2048) * 64 + d;
#pragma unroll
                for (int i = 0; i < 4; ++i) {
                    const int mb = m0 + wm + i * 16 + quad * 4;
#pragma unroll
                    for (int r = 0; r < 4; ++r)
                        kp[(size_t)(mb + r) * 64] = (__bf16)acc[i][j][r];
                }
            }
        } else {
#pragma unroll
            for (int j = 0; j < 4; ++j) {
                const int col = n0 + wn + j * 16 + il - 1024;
                const int hn = col >> 6, d = col & 63;
                __bf16* vp = (__bf16*)c1 + ((size_t)((zz * 16 + hn) * 64 + d)) * 2048;
#pragma unroll
                for (int i = 0; i < 4; ++i) {
                    const int mb = m0 + wm + i * 16 + quad * 4;
                    bf16x4t pk = {(__bf16)acc[i][j][0], (__bf16)acc[i][j][1],
                                  (__bf16)acc[i][j][2], (__bf16)acc[i][j][3]};
                    *(bf16x4t*)(vp + mb) = pk;
                }
            }
        }
    } else { // kind 4: rk
#pragma unroll
        for (int j = 0; j < 4; ++j) {
            const int col = n0 + wn + j * 16 + il;
            const int hn = col >> 6, d = col & 63;
            __bf16* rp = (__bf16*)c0 + ((size_t)hn * 2048) * 64 + d;
#pragma unroll
            for (int i = 0; i < 4; ++i) {
                const int mb = m0 + wm + i * 16 + quad * 4;
#pragma unroll
                for (int r = 0; r < 4; ++r)
                    rp[(size_t)(mb + r) * 64] = (__bf16)acc[i][j][r];
            }
        }
    }
}

// ---------------------------------------------------------------------------
// MFMA flash attention, 3-way j-split (R6).
// Grid (48, NH, BSZ): blockIdx.x = ib3*3 + part; ib swizzled for balance.
// Each part computes tiles [part*nt/3, (part+1)*nt/3) of i-block ib and
// writes unnormalized partials:  Op[part][b][n][ib][i64][d64] f32,
// ml m-plane / l-plane f32.  attn_combine merges the 3 parts.
// LDS: kt 8KB | vt 8KB | rkt 16KB (circular) | scratch 4x3328B = 46080 B.
// 3072 blocks = 4 exact rounds of 768 (3 blocks/CU) -> no dispatch tail.
// ---------------------------------------------------------------------------
__global__ __launch_bounds__(256, 3)
void attn_mfma(const __bf16* __restrict__ qwh, const __bf16* __restrict__ qrh,
               const __bf16* __restrict__ kh, const __bf16* __restrict__ vhT,
               const __bf16* __restrict__ rkh, float* __restrict__ Op,
               float* __restrict__ ml)
{
    extern __shared__ __bf16 smem[];
    __bf16* kt  = smem;            // [64][64] xor-swizzled
    __bf16* vt  = smem + 4096;     // [64][64] xor
    __bf16* rkt = smem + 8192;     // [128][64] xor, circular
    __bf16* sc  = smem + 16384;    // 4 x 1664: per-wave bt[16][104] / pt[16][88]

    const int bx = blockIdx.x;
    const int part = bx % 3;
    const int bx2 = bx / 3;
    const int ib = (bx2 & 1) ? (15 - (bx2 >> 1)) : (bx2 >> 1);
    const int i0 = ib * 64;
    const int n = blockIdx.y, b = blockIdx.z;
    const int tid = threadIdx.x;
    const int w = tid >> 6, l = tid & 63;
    const int il = l & 15, quad = l >> 4;
    const int iw0 = i0 + w * 16;
    const int i_gl = iw0 + il;

    __bf16* btw = sc + w * 1664;   // stride 104
    __bf16* ptw = sc + w * 1664;   // stride 88 (union; exp depends on bt gather)

    const size_t qoff = ((size_t)((b * 16 + n) * QL + iw0 + il)) * 64 + quad * 8;
    bf16x8 qwf0 = *(const bf16x8*)(qwh + qoff);
    bf16x8 qwf1 = *(const bf16x8*)(qwh + qoff + 32);
    bf16x8 qrf0 = *(const bf16x8*)(qrh + qoff);
    bf16x8 qrf1 = *(const bf16x8*)(qrh + qoff + 32);

    f32x4 O[4] = {};
    float m_i = -1e30f, l_i = 0.f;
    const float c = 0.125f * 1.44269504f;   // scale * log2(e)

    const int srow = l >> 3, scl = l & 7;   // staging: 8 rows x 8 chunks / wave
    const __bf16* kbase  = kh  + ((size_t)((b * 16 + n) * KLN)) * 64;
    const __bf16* vbase0 = vhT + ((size_t)((b * 16 + n) * 64)) * KLN;
    const __bf16* rbp    = rkh + ((size_t)(n * KLN)) * 64;
    const int ub = 48 - 16 * w;             // wave's base logical row in rkt

    const int xk0 = ((quad) ^ (il & 7)) << 3;
    const int xk1 = ((quad + 4) ^ (il & 7)) << 3;

    const int nt = ib + 17;                 // total tiles for this i-block
    const int t0 = (part * nt) / 3;
    const int t1 = ((part + 1) * nt) / 3;

    for (int jt = t0; jt < t1; ++jt) {
        const int j0 = jt * 64;
        const int vu0 = j0 - i0 + 960;       // rk row of logical rkt row 0
        const int rot = (jt << 6) & 127;     // circular offset
        __syncthreads();
#pragma unroll
        for (int it = 0; it < 2; ++it) {    // K tile rows j
            const int row = w * 16 + it * 8 + srow;
            g2l16(kt + (w * 16 + it * 8) * 64,
                  kbase + ((size_t)(j0 + row)) * 64 + ((scl ^ srow) << 3));
        }
#pragma unroll
        for (int it = 0; it < 2; ++it) {    // V^T tile rows d
            const int row = w * 16 + it * 8 + srow;
            g2l16(vt + (w * 16 + it * 8) * 64,
                  vbase0 + (size_t)row * KLN + j0 + ((scl ^ srow) << 3));
        }
        if (jt == t0) {                      // full 128-row window fill
#pragma unroll
            for (int it = 0; it < 4; ++it) {
                const int pbase = w * 32 + it * 8;
                const int lrow = ((pbase + srow) - rot) & 127;  // logical row
                int vu = vu0 + lrow;
                vu = vu < 0 ? 0 : (vu > KLN - 1 ? KLN - 1 : vu);
                g2l16(rkt + pbase * 64,
                      rbp + (size_t)vu * 64 + ((scl ^ srow) << 3));
            }
        } else {                             // slide: 64 new rows (logical 64..127)
#pragma unroll
            for (int it = 0; it < 2; ++it) {
                const int row = 64 + w * 16 + it * 8 + srow;     // logical
                int vu = vu0 + row;
                vu = vu < 0 ? 0 : (vu > KLN - 1 ? KLN - 1 : vu);
                const int prow = (64 + w * 16 + it * 8 + rot) & 127;
                g2l16(rkt + prow * 64,
                      rbp + (size_t)vu * 64 + ((scl ^ srow) << 3));
            }
        }
        __syncthreads();

        // ---- AC^T: S^T[j][i] = K·Qw
        f32x4 sf[4];
#pragma unroll
        for (int fr = 0; fr < 4; ++fr) {
            const __bf16* ka = kt + (fr * 16 + il) * 64;
            bf16x8 a0 = *(const bf16x8*)(ka + xk0);
            bf16x8 a1 = *(const bf16x8*)(ka + xk1);
            f32x4 acc = {};
            acc = __builtin_amdgcn_mfma_f32_16x16x32_bf16(a0, qwf0, acc, 0, 0, 0);
            acc = __builtin_amdgcn_mfma_f32_16x16x32_bf16(a1, qwf1, acc, 0, 0, 0);
            sf[fr] = acc;
        }
        // ---- Btilde^T = RK·Qr -> bt[i][u] (b64 stores), circular row index
#pragma unroll
        for (int uf = 0; uf < 5; ++uf) {
            const int prow = ((ub + uf * 16 + il) + rot) & 127;
            const __bf16* ra = rkt + prow * 64;
            bf16x8 a0 = *(const bf16x8*)(ra + xk0);
            bf16x8 a1 = *(const bf16x8*)(ra + xk1);
            f32x4 acc = {};
            acc = __builtin_amdgcn_mfma_f32_16x16x32_bf16(a0, qrf0, acc, 0, 0, 0);
            acc = __builtin_amdgcn_mfma_f32_16x16x32_bf16(a1, qrf1, acc, 0, 0, 0);
            bf16x4t bb = {(__bf16)acc[0], (__bf16)acc[1],
                          (__bf16)acc[2], (__bf16)acc[3]};
            *(bf16x4t*)(btw + il * 104 + uf * 16 + quad * 4) = bb;
        }

        // ---- gather shift (+ mask only on boundary tiles); tile max
        float sv[4][4];
        float tmax = -1e30f;
        if (j0 + 63 > i0 + MEM) {
#pragma unroll
            for (int fr = 0; fr < 4; ++fr)
#pragma unroll
                for (int r = 0; r < 4; ++r) {
                    const int jl_ = fr * 16 + quad * 4 + r;
                    float s = sf[fr][r] + (float)btw[il * 104 + (jl_ - il + 15)];
                    s = (j0 + jl_ > i_gl + MEM) ? -1e30f : s;
                    sv[fr][r] = s;
                    tmax = fmaxf(tmax, s);
                }
        } else {
#pragma unroll
            for (int fr = 0; fr < 4; ++fr)
#pragma unroll
                for (int r = 0; r < 4; ++r) {
                    const int jl_ = fr * 16 + quad * 4 + r;
                    float s = sf[fr][r] + (float)btw[il * 104 + (jl_ - il + 15)];
                    sv[fr][r] = s;
                    tmax = fmaxf(tmax, s);
                }
        }
        tmax = fmaxf(tmax, __shfl_xor(tmax, 16));
        tmax = fmaxf(tmax, __shfl_xor(tmax, 32));
        const float m_new = fmaxf(m_i, tmax);
        const float alpha = exp2f((m_i - m_new) * c);
        float psum = 0.f;
#pragma unroll
        for (int fr = 0; fr < 4; ++fr) {
            bf16x4t p4;
#pragma unroll
            for (int r = 0; r < 4; ++r) {
                float p = exp2f((sv[fr][r] - m_new) * c);
                psum += p;
                p4[r] = (__bf16)p;
            }
            *(bf16x4t*)(ptw + il * 88 + fr * 16 + quad * 4) = p4;
        }
        psum += __shfl_xor(psum, 16);
        psum += __shfl_xor(psum, 32);
        l_i = l_i * alpha + psum;
        m_i = m_new;
#pragma unroll
        for (int df = 0; df < 4; ++df) O[df] *= alpha;

        // ---- O^T += V^T · P
        bf16x8 p0 = *(const bf16x8*)(ptw + il * 88 + quad * 8);
        bf16x8 p1 = *(const bf16x8*)(ptw + il * 88 + 32 + quad * 8);
#pragma unroll
        for (int df = 0; df < 4; ++df) {
            const __bf16* va = vt + (df * 16 + il) * 64;
            bf16x8 a0 = *(const bf16x8*)(va + xk0);
            bf16x8 a1 = *(const bf16x8*)(va + xk1);
            O[df] = __builtin_amdgcn_mfma_f32_16x16x32_bf16(a0, p0, O[df], 0, 0, 0);
            O[df] = __builtin_amdgcn_mfma_f32_16x16x32_bf16(a1, p1, O[df], 0, 0, 0);
        }
    }

    // ---- write partials (unnormalized)
    const int i_local = w * 16 + il;
    float* opb = Op + ((((size_t)part * BSZ + b) * NH + n) * 16 + ib) * 4096
                    + (size_t)i_local * 64 + quad * 4;
#pragma unroll
    for (int df = 0; df < 4; ++df)
        *(f32x4*)(opb + df * 16) = O[df];
    if (quad == 0) {
        const size_t midx = ((((size_t)part * BSZ + b) * NH + n) * 16 + ib) * 64
                            + i_local;
        ml[midx]          = m_i;
        ml[196608 + midx] = l_i;   // l-plane offset = 3*4*16*16*64
    }
}

// ---------------------------------------------------------------------------
// Combine 3 attention partials -> avh bf16 [b][i][n*64+d].
// Grid (QL/4, NH, BSZ), 256 threads: 4 i-rows x 64 d per block.
// ---------------------------------------------------------------------------
__global__ __launch_bounds__(256)
void attn_combine(const float* __restrict__ Op, const float* __restrict__ ml,
                  __bf16* __restrict__ av)
{
    const int tid = threadIdx.x;
    const int i = blockIdx.x * 4 + (tid >> 6);
    const int d = tid & 63;
    const int n = blockIdx.y, b = blockIdx.z;
    const int ib = i >> 6, il_ = i & 63;
    const float c = 0.125f * 1.44269504f;

    const size_t mb = (((size_t)b * NH + n) * 16 + ib) * 64 + il_;
    const float m0 = ml[mb], m1 = ml[mb + 65536], m2 = ml[mb + 131072];
    const float* lp = ml + 196608;
    const float l0 = lp[mb], l1 = lp[mb + 65536], l2 = lp[mb + 131072];
    const float ms = fmaxf(m0, fmaxf(m1, m2));
    const float w0 = exp2f((m0 - ms) * c);
    const float w1 = exp2f((m1 - ms) * c);
    const float w2 = exp2f((m2 - ms) * c);
    const float ls = w0 * l0 + w1 * l1 + w2 * l2;

    const size_t ob = (((size_t)b * NH + n) * 16 + ib) * 4096
                      + (size_t)il_ * 64 + d;
    const float o = w0 * Op[ob] + w1 * Op[ob + 4194304]
                  + w2 * Op[ob + 2 * 4194304];
    av[((size_t)(b * QL + i)) * DM + n * 64 + d] = (__bf16)(o / ls);
}

// ---------------------------------------------------------------------------
// Workspace (MB offsets, ~140 MB total):
//  0 wbh(16) | 16 rbh(4) | 20 WqT(2) | 22 WkvT(4) | 26 WrT(2) | 28 WoT(2)
//  30 qwh(8) | 38 qrh(8) | 46 kh(16) | 62 vhT(16) | 78 rkh(4) | 82 avh(8)
//  90 Op(48) | 138 ml(1.5)
// ---------------------------------------------------------------------------
extern "C" void kernel_launch(void* const* d_in, const int* in_sizes, int n_in,
                              void* d_out, int out_size, void* d_ws, size_t ws_size,
                              hipStream_t stream)
{
    const float* w   = (const float*)d_in[0];
    const float* r   = (const float*)d_in[1];
    const float* bwb = (const float*)d_in[2];
    const float* brb = (const float*)d_in[3];
    const float* Wq  = (const float*)d_in[4];
    const float* Wkv = (const float*)d_in[5];
    const float* Wr  = (const float*)d_in[6];
    const float* Wo  = (const float*)d_in[7];
    float* out = (float*)d_out;

    char* ws = (char*)d_ws;
    __bf16* wbh  = (__bf16*)(ws);
    __bf16* rbh  = (__bf16*)(ws + ((size_t)16 << 20));
    __bf16* WqT  = (__bf16*)(ws + ((size_t)20 << 20));
    __bf16* WkvT = (__bf16*)(ws + ((size_t)22 << 20));
    __bf16* WrT  = (__bf16*)(ws + ((size_t)26 << 20));
    __bf16* WoT  = (__bf16*)(ws + ((size_t)28 << 20));
    __bf16* qwh  = (__bf16*)(ws + ((size_t)30 << 20));
    __bf16* qrh  = (__bf16*)(ws + ((size_t)38 << 20));
    __bf16* kh   = (__bf16*)(ws + ((size_t)46 << 20));
    __bf16* vhT  = (__bf16*)(ws + ((size_t)62 << 20));
    __bf16* rkh  = (__bf16*)(ws + ((size_t)78 << 20));
    __bf16* avh  = (__bf16*)(ws + ((size_t)82 << 20));
    float*  Op   = (float*)(ws + ((size_t)90 << 20));
    float*  mlb  = (float*)(ws + ((size_t)138 << 20));

    dim3 blk(256);
    cast_wr<<<5120, blk, 0, stream>>>(w, r, wbh, rbh);
    tcast_all<<<dim3(32, 16, 4), blk, 0, stream>>>(Wq, Wr, Wo, Wkv,
                                                   WqT, WrT, WoT, WkvT);
    // q projection -> qwh/qrh (biases fused)
    gemm_bf16<<<dim3(8, 8, 4), blk, 0, stream>>>(
        wbh + (size_t)MEM * DM, WqT, qwh, qrh, bwb, brb,
        QL, DM, DM, (long)KLN * DM, 0, 2);
    // kv projection -> kh / vhT
    gemm_bf16<<<dim3(16, 16, 4), blk, 0, stream>>>(
        wbh, WkvT, kh, vhT, bwb, brb,
        KLN, 2 * DM, DM, (long)KLN * DM, 0, 3);
    // rk projection -> rkh
    gemm_bf16<<<dim3(8, 16, 1), blk, 0, stream>>>(
        rbh, WrT, rkh, rkh, bwb, brb,
        KLN, DM, DM, 0, 0, 4);
    // attention: 3-way j-split partials, then combine
    attn_mfma<<<dim3(48, 16, 4), blk, 46080, stream>>>(
        qwh, qrh, kh, vhT, rkh, Op, mlb);
    attn_combine<<<dim3(256, 16, 4), blk, 0, stream>>>(Op, mlb, avh);
    // out projection (f32)
    gemm_bf16<<<dim3(8, 8, 4), blk, 0, stream>>>(
        avh, WoT, out, out, bwb, brb,
        QL, DM, DM, (long)QL * DM, (long)QL * DM, 0);
}

// Round 7
// 393.725 us; speedup vs baseline: 7.3958x; 1.0350x over previous
//
#include <hip/hip_runtime.h>

// Problem constants (Transformer-XL attention)
constexpr int BSZ  = 4;
constexpr int NH   = 16;
constexpr int DH   = 64;
constexpr int QL   = 1024;
constexpr int KLN  = 2048;
constexpr int DM   = 1024;   // d_model = NH*DH
constexpr int MEM  = 1024;   // KLEN - QLEN

typedef __bf16 bf16x8  __attribute__((ext_vector_type(8)));
typedef __bf16 bf16x4t __attribute__((ext_vector_type(4)));
typedef float  f32x4   __attribute__((ext_vector_type(4)));

// async global->LDS, 16B per lane; LDS dst is wave-uniform base + lane*16
__device__ __forceinline__ void g2l16(__bf16* lds, const __bf16* g) {
    __builtin_amdgcn_global_load_lds(
        (const __attribute__((address_space(1))) unsigned int*)g,
        (__attribute__((address_space(3))) unsigned int*)lds, 16, 0, 0);
}

// ---------------------------------------------------------------------------
// prep: one launch. Blocks [0,5120): cast w,r -> bf16. Blocks [5120,7168):
// transpose-cast the 4 weights (z = t>>9: 0 Wq, 1 Wr, 2 Wo, 3 Wkv).
// ---------------------------------------------------------------------------
__global__ __launch_bounds__(256)
void prep(const float* __restrict__ w, const float* __restrict__ r,
          const float* __restrict__ Wq, const float* __restrict__ Wr,
          const float* __restrict__ Wo, const float* __restrict__ Wkv,
          __bf16* __restrict__ wbh, __bf16* __restrict__ rbh,
          __bf16* __restrict__ WqT, __bf16* __restrict__ WrT,
          __bf16* __restrict__ WoT, __bf16* __restrict__ WkvT)
{
    __shared__ __bf16 t[64 * 72];
    const int id = blockIdx.x;
    if (id < 5120) {
        const float* in; __bf16* out; size_t i;
        if (id < 4096) { in = w; out = wbh; i = ((size_t)id * 256 + threadIdx.x) * 8; }
        else { in = r; out = rbh; i = ((size_t)(id - 4096) * 256 + threadIdx.x) * 8; }
        float4 a = *(const float4*)(in + i);
        float4 b = *(const float4*)(in + i + 4);
        bf16x8 y = {(__bf16)a.x, (__bf16)a.y, (__bf16)a.z, (__bf16)a.w,
                    (__bf16)b.x, (__bf16)b.y, (__bf16)b.z, (__bf16)b.w};
        *(bf16x8*)(out + i) = y;
        return;
    }
    const int tt = id - 5120;
    const int z = tt >> 9, rem = tt & 511;
    const int xx = rem & 31, yy = rem >> 5;
    const float* in; __bf16* out; int N;
    if (z == 0)      { in = Wq;  out = WqT;  N = 1024; }
    else if (z == 1) { in = Wr;  out = WrT;  N = 1024; }
    else if (z == 2) { in = Wo;  out = WoT;  N = 1024; }
    else             { in = Wkv; out = WkvT; N = 2048; }
    if (xx * 64 >= N) return;
    const int n0 = xx * 64, k0 = yy * 64;
    const int row = threadIdx.x >> 2, seg = (threadIdx.x & 3) << 4;
    const float* src = in + (long)(k0 + row) * N + n0 + seg;
#pragma unroll
    for (int u = 0; u < 16; u += 4) {
        float4 x = *(const float4*)(src + u);
        t[(seg + u + 0) * 72 + row] = (__bf16)x.x;
        t[(seg + u + 1) * 72 + row] = (__bf16)x.y;
        t[(seg + u + 2) * 72 + row] = (__bf16)x.z;
        t[(seg + u + 3) * 72 + row] = (__bf16)x.w;
    }
    __syncthreads();
    __bf16* dst = out + (long)(n0 + row) * 1024 + k0 + seg;
    *(uint4*)(dst)     = *(const uint4*)(t + row * 72 + seg);
    *(uint4*)(dst + 8) = *(const uint4*)(t + row * 72 + seg + 8);
}

// ---------------------------------------------------------------------------
// Shared GEMM core: 128x128 tile, BK=32, 4 waves, K-loop with
// global_load_lds + XOR-swizzled LDS.  Accumulates into acc[4][4].
// ---------------------------------------------------------------------------
__device__ __forceinline__ void gemm_core(
    const __bf16* __restrict__ A, const __bf16* __restrict__ BT,
    __bf16* As, __bf16* Bs, int m0, int n0, int K, f32x4 (&acc)[4][4])
{
    const int tid = threadIdx.x, w = tid >> 6, l = tid & 63;
    const int il = l & 15, quad = l >> 4;
    const int wm = (w >> 1) * 64, wn = (w & 1) * 64;
    const int lr = l >> 2, kc = (l & 3) ^ (lr & 3);

    const __bf16* ag = A  + (long)(m0 + w * 32 + lr) * K + kc * 8;
    const __bf16* bg = BT + (long)(n0 + w * 32 + lr) * K + kc * 8;
    __bf16* al0 = As + (w * 32) * 32;
    __bf16* al1 = As + (w * 32 + 16) * 32;
    __bf16* bl0 = Bs + (w * 32) * 32;
    __bf16* bl1 = Bs + (w * 32 + 16) * 32;
    const int rsw = il & 3;

    for (int k0 = 0; k0 < K; k0 += 32) {
        __syncthreads();
        g2l16(al0, ag + k0);
        g2l16(al1, ag + k0 + 16 * K);
        g2l16(bl0, bg + k0);
        g2l16(bl1, bg + k0 + 16 * K);
        __syncthreads();

        bf16x8 af[4], bf[4];
#pragma unroll
        for (int f = 0; f < 4; ++f) {
            af[f] = *(const bf16x8*)(As + (wm + f * 16 + il) * 32 + ((quad ^ rsw) << 3));
            bf[f] = *(const bf16x8*)(Bs + (wn + f * 16 + il) * 32 + ((quad ^ rsw) << 3));
        }
#pragma unroll
        for (int i = 0; i < 4; ++i)
#pragma unroll
            for (int j = 0; j < 4; ++j)
                acc[i][j] = __builtin_amdgcn_mfma_f32_16x16x32_bf16(
                    af[i], bf[j], acc[i][j], 0, 0, 0);
    }
}

// ---------------------------------------------------------------------------
// Merged projection GEMM: 1408 blocks.
//   [0,1024):  kv = w @ Wkv   -> kh / vhT   (16x16x4 tiles)
//   [1024,1280): q = w[:,-QL:] @ Wq -> qwh/qrh (+biases)  (8x8x4)
//   [1280,1408): rk = r @ Wr  -> rkh        (8x16)
// ---------------------------------------------------------------------------
__global__ __launch_bounds__(256, 2)
void gemm_proj(const __bf16* __restrict__ wbh, const __bf16* __restrict__ rbh,
               const __bf16* __restrict__ WqT, const __bf16* __restrict__ WkvT,
               const __bf16* __restrict__ WrT,
               __bf16* __restrict__ qwh, __bf16* __restrict__ qrh,
               __bf16* __restrict__ kh, __bf16* __restrict__ vhT,
               __bf16* __restrict__ rkh,
               const float* __restrict__ bw, const float* __restrict__ br)
{
    __shared__ __bf16 As[128 * 32];
    __shared__ __bf16 Bs[128 * 32];
    const int id = blockIdx.x;
    const __bf16 *A, *BT;
    int m0, n0, zz, kind, N;
    if (id < 1024) {
        n0 = (id & 15) * 128; m0 = ((id >> 4) & 15) * 128; zz = id >> 8;
        A = wbh + (size_t)zz * KLN * DM; BT = WkvT; kind = 3; N = 2048;
    } else if (id < 1280) {
        const int t = id - 1024;
        n0 = (t & 7) * 128; m0 = ((t >> 3) & 7) * 128; zz = t >> 6;
        A = wbh + (size_t)zz * KLN * DM + (size_t)MEM * DM; BT = WqT; kind = 2; N = 1024;
    } else {
        const int t = id - 1280;
        n0 = (t & 7) * 128; m0 = (t >> 3) * 128; zz = 0;
        A = rbh; BT = WrT; kind = 4; N = 1024;
    }

    f32x4 acc[4][4] = {};
    gemm_core(A, BT, As, Bs, m0, n0, DM, acc);

    const int tid = threadIdx.x, w = tid >> 6, l = tid & 63;
    const int il = l & 15, quad = l >> 4;
    const int wm = (w >> 1) * 64, wn = (w & 1) * 64;

    if (kind == 2) {
#pragma unroll
        for (int j = 0; j < 4; ++j) {
            const int col = n0 + wn + j * 16 + il;
            const int hn = col >> 6, d = col & 63;
            const float bwv = bw[col], brv = br[col];
            __bf16* q1 = qwh + ((size_t)(zz * 16 + hn) * 1024) * 64 + d;
            __bf16* q2 = qrh + ((size_t)(zz * 16 + hn) * 1024) * 64 + d;
#pragma unroll
            for (int i = 0; i < 4; ++i) {
                const int mb = m0 + wm + i * 16 + quad * 4;
#pragma unroll
                for (int rr = 0; rr < 4; ++rr) {
                    float v = acc[i][j][rr];
                    q1[(size_t)(mb + rr) * 64] = (__bf16)(v + bwv);
                    q2[(size_t)(mb + rr) * 64] = (__bf16)(v + brv);
                }
            }
        }
    } else if (kind == 3) {
        if (n0 + wn < 1024) {
#pragma unroll
            for (int j = 0; j < 4; ++j) {
                const int col = n0 + wn + j * 16 + il;
                const int hn = col >> 6, d = col & 63;
                __bf16* kp = kh + ((size_t)(zz * 16 + hn) * 2048) * 64 + d;
#pragma unroll
                for (int i = 0; i < 4; ++i) {
                    const int mb = m0 + wm + i * 16 + quad * 4;
#pragma unroll
                    for (int rr = 0; rr < 4; ++rr)
                        kp[(size_t)(mb + rr) * 64] = (__bf16)acc[i][j][rr];
                }
            }
        } else {
#pragma unroll
            for (int j = 0; j < 4; ++j) {
                const int col = n0 + wn + j * 16 + il - 1024;
                const int hn = col >> 6, d = col & 63;
                __bf16* vp = vhT + ((size_t)((zz * 16 + hn) * 64 + d)) * 2048;
#pragma unroll
                for (int i = 0; i < 4; ++i) {
                    const int mb = m0 + wm + i * 16 + quad * 4;
                    bf16x4t pk = {(__bf16)acc[i][j][0], (__bf16)acc[i][j][1],
                                  (__bf16)acc[i][j][2], (__bf16)acc[i][j][3]};
                    *(bf16x4t*)(vp + mb) = pk;
                }
            }
        }
    } else { // kind 4
#pragma unroll
        for (int j = 0; j < 4; ++j) {
            const int col = n0 + wn + j * 16 + il;
            const int hn = col >> 6, d = col & 63;
            __bf16* rp = rkh + ((size_t)hn * 2048) * 64 + d;
#pragma unroll
            for (int i = 0; i < 4; ++i) {
                const int mb = m0 + wm + i * 16 + quad * 4;
#pragma unroll
                for (int rr = 0; rr < 4; ++rr)
                    rp[(size_t)(mb + rr) * 64] = (__bf16)acc[i][j][rr];
            }
        }
    }
}

// ---------------------------------------------------------------------------
// Output projection: out = avh @ WoT^T, f32 C.  Grid (8,8,4).
// ---------------------------------------------------------------------------
__global__ __launch_bounds__(256, 2)
void gemm_out(const __bf16* __restrict__ avh, const __bf16* __restrict__ WoT,
              float* __restrict__ C)
{
    __shared__ __bf16 As[128 * 32];
    __shared__ __bf16 Bs[128 * 32];
    const int zz = blockIdx.z;
    const __bf16* A = avh + (size_t)zz * QL * DM;
    const int m0 = blockIdx.y * 128, n0 = blockIdx.x * 128;

    f32x4 acc[4][4] = {};
    gemm_core(A, WoT, As, Bs, m0, n0, DM, acc);

    const int tid = threadIdx.x, w = tid >> 6, l = tid & 63;
    const int il = l & 15, quad = l >> 4;
    const int wm = (w >> 1) * 64, wn = (w & 1) * 64;
    float* Cb = C + (size_t)zz * QL * DM;
#pragma unroll
    for (int i = 0; i < 4; ++i)
#pragma unroll
        for (int j = 0; j < 4; ++j) {
            float* cp = Cb + (long)(m0 + wm + i * 16 + quad * 4) * DM
                           + n0 + wn + j * 16 + il;
#pragma unroll
            for (int rr = 0; rr < 4; ++rr) cp[(long)rr * DM] = acc[i][j][rr];
        }
}

// ---------------------------------------------------------------------------
// MFMA flash attention, R7: 128-i blocks, 2 i-frags/wave, split-2 over j.
// Grid (16, NH, BSZ): bx = ib2*2 + part, ib pair-swizzled over 8.
// rkt: 192-row circular window (rot in {0,64,128}), slide 64 rows/tile.
// Per-(wave,g) scratch [16][88] unions Btilde (u 0..79) and P (j 0..63).
// LDS: kt 8KB | vt 8KB | rkt 24KB | scratch 22KB = 63488 B -> 2 blocks/CU.
// 1024 blocks = exactly 2 rounds at 2/CU.
// ---------------------------------------------------------------------------
__global__ __launch_bounds__(256, 2)
void attn_mfma(const __bf16* __restrict__ qwh, const __bf16* __restrict__ qrh,
               const __bf16* __restrict__ kh, const __bf16* __restrict__ vhT,
               const __bf16* __restrict__ rkh, float* __restrict__ Op,
               float* __restrict__ ml)
{
    extern __shared__ __bf16 smem[];
    __bf16* kt  = smem;            // [64][64] xor-swizzled
    __bf16* vt  = smem + 4096;     // [64][64] xor
    __bf16* rkt = smem + 8192;     // [192][64] xor, circular
    __bf16* sc  = smem + 20480;    // 4 waves x 2 g x 1408 elems

    const int bx = blockIdx.x;
    const int part = bx & 1;
    const int bx2 = bx >> 1;                     // 0..7
    const int ib = (bx2 & 1) ? (7 - (bx2 >> 1)) : (bx2 >> 1);
    const int i0 = ib * 128;
    const int n = blockIdx.y, b = blockIdx.z;
    const int tid = threadIdx.x;
    const int w = tid >> 6, l = tid & 63;
    const int il = l & 15, quad = l >> 4;
    const int iw0 = i0 + w * 32;

    // persistent Q fragments, 2 i-frags per wave
    bf16x8 qwf[2][2], qrf[2][2];
#pragma unroll
    for (int g = 0; g < 2; ++g) {
        const size_t qoff =
            ((size_t)((b * 16 + n) * QL + iw0 + 16 * g + il)) * 64 + quad * 8;
        qwf[g][0] = *(const bf16x8*)(qwh + qoff);
        qwf[g][1] = *(const bf16x8*)(qwh + qoff + 32);
        qrf[g][0] = *(const bf16x8*)(qrh + qoff);
        qrf[g][1] = *(const bf16x8*)(qrh + qoff + 32);
    }

    f32x4 O[2][4] = {};
    float m_i[2] = {-1e30f, -1e30f}, l_i[2] = {0.f, 0.f};
    const float c = 0.125f * 1.44269504f;        // scale * log2(e)

    const int srow = l >> 3, scl = l & 7;        // staging: 8 rows x 8 chunks
    const __bf16* kbase  = kh  + ((size_t)((b * 16 + n) * KLN)) * 64;
    const __bf16* vbase0 = vhT + ((size_t)((b * 16 + n) * 64)) * KLN;
    const __bf16* rbp    = rkh + ((size_t)(n * KLN)) * 64;

    const int xk0 = ((quad) ^ (il & 7)) << 3;
    const int xk1 = ((quad + 4) ^ (il & 7)) << 3;

    const int nt = 2 * ib + 18;
    const int t0 = (part * nt) / 2;
    const int t1 = ((part + 1) * nt) / 2;
    int rot = (t0 % 3) * 64;                     // circular offset for tile t0

    for (int jt = t0; jt < t1; ++jt) {
        const int j0 = jt * 64;
        const int vu0 = j0 - i0 + 896;           // rk row of logical rkt row 0
        __syncthreads();
#pragma unroll
        for (int it = 0; it < 2; ++it) {         // K tile rows j
            const int row = w * 16 + it * 8 + srow;
            g2l16(kt + (w * 16 + it * 8) * 64,
                  kbase + ((size_t)(j0 + row)) * 64 + ((scl ^ srow) << 3));
        }
#pragma unroll
        for (int it = 0; it < 2; ++it) {         // V^T tile rows d
            const int row = w * 16 + it * 8 + srow;
            g2l16(vt + (w * 16 + it * 8) * 64,
                  vbase0 + (size_t)row * KLN + j0 + ((scl ^ srow) << 3));
        }
        if (jt == t0) {                          // full 192-row window fill
#pragma unroll
            for (int it = 0; it < 6; ++it) {
                const int lbase = w * 48 + it * 8;
                int pb = lbase + rot; if (pb >= 192) pb -= 192;
                int vu = vu0 + lbase + srow;
                vu = vu < 0 ? 0 : (vu > KLN - 1 ? KLN - 1 : vu);
                g2l16(rkt + pb * 64,
                      rbp + (size_t)vu * 64 + ((scl ^ srow) << 3));
            }
        } else {                                 // slide: logical rows 128..191
#pragma unroll
            for (int it = 0; it < 2; ++it) {
                const int lbase = 128 + w * 16 + it * 8;
                int pb = lbase + rot; if (pb >= 192) pb -= 192;
                int vu = vu0 + lbase + srow;
                vu = vu < 0 ? 0 : (vu > KLN - 1 ? KLN - 1 : vu);
                g2l16(rkt + pb * 64,
                      rbp + (size_t)vu * 64 + ((scl ^ srow) << 3));
            }
        }
        __syncthreads();

        const bool edge = (j0 + 63 > i0 + MEM);

#pragma unroll
        for (int g = 0; g < 2; ++g) {
            __bf16* scg = sc + (w * 2 + g) * 1408;
            const int i_gl = iw0 + 16 * g + il;

            // ---- AC^T: S^T[j][i] = K·Qw
            f32x4 sf[4];
#pragma unroll
            for (int fr = 0; fr < 4; ++fr) {
                const __bf16* ka = kt + (fr * 16 + il) * 64;
                bf16x8 a0 = *(const bf16x8*)(ka + xk0);
                bf16x8 a1 = *(const bf16x8*)(ka + xk1);
                f32x4 acc = {};
                acc = __builtin_amdgcn_mfma_f32_16x16x32_bf16(a0, qwf[g][0], acc, 0, 0, 0);
                acc = __builtin_amdgcn_mfma_f32_16x16x32_bf16(a1, qwf[g][1], acc, 0, 0, 0);
                sf[fr] = acc;
            }
            // ---- Btilde^T = RK·Qr -> bt[i][u'] (b64 stores)
            const int ubg = 112 - 32 * w - 16 * g;
#pragma unroll
            for (int uf = 0; uf < 5; ++uf) {
                int pr = ubg + uf * 16 + il + rot; if (pr >= 192) pr -= 192;
                const __bf16* ra = rkt + pr * 64;
                bf16x8 a0 = *(const bf16x8*)(ra + xk0);
                bf16x8 a1 = *(const bf16x8*)(ra + xk1);
                f32x4 acc = {};
                acc = __builtin_amdgcn_mfma_f32_16x16x32_bf16(a0, qrf[g][0], acc, 0, 0, 0);
                acc = __builtin_amdgcn_mfma_f32_16x16x32_bf16(a1, qrf[g][1], acc, 0, 0, 0);
                bf16x4t bb = {(__bf16)acc[0], (__bf16)acc[1],
                              (__bf16)acc[2], (__bf16)acc[3]};
                *(bf16x4t*)(scg + il * 88 + uf * 16 + quad * 4) = bb;
            }

            // ---- gather shift (+ mask on boundary tiles); tile max
            float sv[4][4];
            float tmax = -1e30f;
#pragma unroll
            for (int fr = 0; fr < 4; ++fr)
#pragma unroll
                for (int rr = 0; rr < 4; ++rr) {
                    const int jl_ = fr * 16 + quad * 4 + rr;
                    float s = sf[fr][rr] + (float)scg[il * 88 + (jl_ - il + 15)];
                    if (edge) s = (j0 + jl_ > i_gl + MEM) ? -1e30f : s;
                    sv[fr][rr] = s;
                    tmax = fmaxf(tmax, s);
                }
            tmax = fmaxf(tmax, __shfl_xor(tmax, 16));
            tmax = fmaxf(tmax, __shfl_xor(tmax, 32));
            const float m_new = fmaxf(m_i[g], tmax);
            const float alpha = exp2f((m_i[g] - m_new) * c);
            float psum = 0.f;
#pragma unroll
            for (int fr = 0; fr < 4; ++fr) {
                bf16x4t p4;
#pragma unroll
                for (int rr = 0; rr < 4; ++rr) {
                    float p = exp2f((sv[fr][rr] - m_new) * c);
                    psum += p;
                    p4[rr] = (__bf16)p;
                }
                // overwrites bt region: safe, p depends on the bt gather
                *(bf16x4t*)(scg + il * 88 + fr * 16 + quad * 4) = p4;
            }
            psum += __shfl_xor(psum, 16);
            psum += __shfl_xor(psum, 32);
            l_i[g] = l_i[g] * alpha + psum;
            m_i[g] = m_new;
#pragma unroll
            for (int df = 0; df < 4; ++df) O[g][df] *= alpha;

            // ---- O^T += V^T · P
            bf16x8 p0 = *(const bf16x8*)(scg + il * 88 + quad * 8);
            bf16x8 p1 = *(const bf16x8*)(scg + il * 88 + 32 + quad * 8);
#pragma unroll
            for (int df = 0; df < 4; ++df) {
                const __bf16* va = vt + (df * 16 + il) * 64;
                bf16x8 a0 = *(const bf16x8*)(va + xk0);
                bf16x8 a1 = *(const bf16x8*)(va + xk1);
                O[g][df] = __builtin_amdgcn_mfma_f32_16x16x32_bf16(a0, p0, O[g][df], 0, 0, 0);
                O[g][df] = __builtin_amdgcn_mfma_f32_16x16x32_bf16(a1, p1, O[g][df], 0, 0, 0);
            }
        }
        rot += 64; if (rot >= 192) rot -= 192;
    }

    // ---- write partials (unnormalized)
#pragma unroll
    for (int g = 0; g < 2; ++g) {
        const int iL = w * 32 + 16 * g + il;
        float* opb = Op + (size_t)part * 4194304
                        + ((((size_t)b * NH + n) * 8 + ib)) * 8192
                        + (size_t)iL * 64 + quad * 4;
#pragma unroll
        for (int df = 0; df < 4; ++df)
            *(f32x4*)(opb + df * 16) = O[g][df];
        if (quad == 0) {
            const size_t base = (((size_t)b * NH + n) * 8 + ib) * 128 + iL;
            ml[(size_t)part * 65536 + base]          = m_i[g];
            ml[131072 + (size_t)part * 65536 + base] = l_i[g];
        }
    }
}

// ---------------------------------------------------------------------------
// Combine 2 attention partials -> avh bf16.  Grid (QL/4, NH, BSZ).
// ---------------------------------------------------------------------------
__global__ __launch_bounds__(256)
void attn_combine(const float* __restrict__ Op, const float* __restrict__ ml,
                  __bf16* __restrict__ av)
{
    const int tid = threadIdx.x;
    const int i = blockIdx.x * 4 + (tid >> 6);
    const int d = tid & 63;
    const int n = blockIdx.y, b = blockIdx.z;
    const int ib = i >> 7, iL = i & 127;
    const float c = 0.125f * 1.44269504f;

    const size_t mb = (((size_t)b * NH + n) * 8 + ib) * 128 + iL;
    const float m0 = ml[mb], m1 = ml[mb + 65536];
    const float l0 = ml[131072 + mb], l1 = ml[131072 + 65536 + mb];
    const float ms = fmaxf(m0, m1);
    const float w0 = exp2f((m0 - ms) * c);
    const float w1 = exp2f((m1 - ms) * c);
    const float ls = w0 * l0 + w1 * l1;

    const size_t ob = (((size_t)b * NH + n) * 8 + ib) * 8192
                      + (size_t)iL * 64 + d;
    const float o = w0 * Op[ob] + w1 * Op[ob + 4194304];
    av[((size_t)(b * QL + i)) * DM + n * 64 + d] = (__bf16)(o / ls);
}

// ---------------------------------------------------------------------------
// Workspace (MB offsets, ~123 MB total):
//  0 wbh(16) | 16 rbh(4) | 20 WqT(2) | 22 WkvT(4) | 26 WrT(2) | 28 WoT(2)
//  30 qwh(8) | 38 qrh(8) | 46 kh(16) | 62 vhT(16) | 78 rkh(4) | 82 avh(8)
//  90 Op(32) | 122 ml(1)
// ---------------------------------------------------------------------------
extern "C" void kernel_launch(void* const* d_in, const int* in_sizes, int n_in,
                              void* d_out, int out_size, void* d_ws, size_t ws_size,
                              hipStream_t stream)
{
    const float* w   = (const float*)d_in[0];
    const float* r   = (const float*)d_in[1];
    const float* bwb = (const float*)d_in[2];
    const float* brb = (const float*)d_in[3];
    const float* Wq  = (const float*)d_in[4];
    const float* Wkv = (const float*)d_in[5];
    const float* Wr  = (const float*)d_in[6];
    const float* Wo  = (const float*)d_in[7];
    float* out = (float*)d_out;

    char* ws = (char*)d_ws;
    __bf16* wbh  = (__bf16*)(ws);
    __bf16* rbh  = (__bf16*)(ws + ((size_t)16 << 20));
    __bf16* WqT  = (__bf16*)(ws + ((size_t)20 << 20));
    __bf16* WkvT = (__bf16*)(ws + ((size_t)22 << 20));
    __bf16* WrT  = (__bf16*)(ws + ((size_t)26 << 20));
    __bf16* WoT  = (__bf16*)(ws + ((size_t)28 << 20));
    __bf16* qwh  = (__bf16*)(ws + ((size_t)30 << 20));
    __bf16* qrh  = (__bf16*)(ws + ((size_t)38 << 20));
    __bf16* kh   = (__bf16*)(ws + ((size_t)46 << 20));
    __bf16* vhT  = (__bf16*)(ws + ((size_t)62 << 20));
    __bf16* rkh  = (__bf16*)(ws + ((size_t)78 << 20));
    __bf16* avh  = (__bf16*)(ws + ((size_t)82 << 20));
    float*  Op   = (float*)(ws + ((size_t)90 << 20));
    float*  mlb  = (float*)(ws + ((size_t)122 << 20));

    dim3 blk(256);
    prep<<<7168, blk, 0, stream>>>(w, r, Wq, Wr, Wo, Wkv,
                                   wbh, rbh, WqT, WrT, WoT, WkvT);
    gemm_proj<<<1408, blk, 0, stream>>>(wbh, rbh, WqT, WkvT, WrT,
                                        qwh, qrh, kh, vhT, rkh, bwb, brb);
    attn_mfma<<<dim3(16, 16, 4), blk, 63488, stream>>>(
        qwh, qrh, kh, vhT, rkh, Op, mlb);
    attn_combine<<<dim3(256, 16, 4), blk, 0, stream>>>(Op, mlb, avh);
    gemm_out<<<dim3(8, 8, 4), blk, 0, stream>>>(avh, WoT, out);
}

// Round 8
// 392.397 us; speedup vs baseline: 7.4208x; 1.0034x over previous
//
#include <hip/hip_runtime.h>

// Problem constants (Transformer-XL attention)
constexpr int BSZ  = 4;
constexpr int NH   = 16;
constexpr int DH   = 64;
constexpr int QL   = 1024;
constexpr int KLN  = 2048;
constexpr int DM   = 1024;   // d_model = NH*DH
constexpr int MEM  = 1024;   // KLEN - QLEN

typedef __bf16 bf16x8  __attribute__((ext_vector_type(8)));
typedef __bf16 bf16x4t __attribute__((ext_vector_type(4)));
typedef float  f32x4   __attribute__((ext_vector_type(4)));

// async global->LDS, 16B per lane; LDS dst is wave-uniform base + lane*16
__device__ __forceinline__ void g2l16(__bf16* lds, const __bf16* g) {
    __builtin_amdgcn_global_load_lds(
        (const __attribute__((address_space(1))) unsigned int*)g,
        (__attribute__((address_space(3))) unsigned int*)lds, 16, 0, 0);
}

// ---------------------------------------------------------------------------
// prep: one launch. Blocks [0,5120): cast w,r -> bf16. Blocks [5120,7168):
// transpose-cast the 4 weights (z = t>>9: 0 Wq, 1 Wr, 2 Wo, 3 Wkv).
// ---------------------------------------------------------------------------
__global__ __launch_bounds__(256)
void prep(const float* __restrict__ w, const float* __restrict__ r,
          const float* __restrict__ Wq, const float* __restrict__ Wr,
          const float* __restrict__ Wo, const float* __restrict__ Wkv,
          __bf16* __restrict__ wbh, __bf16* __restrict__ rbh,
          __bf16* __restrict__ WqT, __bf16* __restrict__ WrT,
          __bf16* __restrict__ WoT, __bf16* __restrict__ WkvT)
{
    __shared__ __bf16 t[64 * 72];
    const int id = blockIdx.x;
    if (id < 5120) {
        const float* in; __bf16* out; size_t i;
        if (id < 4096) { in = w; out = wbh; i = ((size_t)id * 256 + threadIdx.x) * 8; }
        else { in = r; out = rbh; i = ((size_t)(id - 4096) * 256 + threadIdx.x) * 8; }
        float4 a = *(const float4*)(in + i);
        float4 b = *(const float4*)(in + i + 4);
        bf16x8 y = {(__bf16)a.x, (__bf16)a.y, (__bf16)a.z, (__bf16)a.w,
                    (__bf16)b.x, (__bf16)b.y, (__bf16)b.z, (__bf16)b.w};
        *(bf16x8*)(out + i) = y;
        return;
    }
    const int tt = id - 5120;
    const int z = tt >> 9, rem = tt & 511;
    const int xx = rem & 31, yy = rem >> 5;
    const float* in; __bf16* out; int N;
    if (z == 0)      { in = Wq;  out = WqT;  N = 1024; }
    else if (z == 1) { in = Wr;  out = WrT;  N = 1024; }
    else if (z == 2) { in = Wo;  out = WoT;  N = 1024; }
    else             { in = Wkv; out = WkvT; N = 2048; }
    if (xx * 64 >= N) return;
    const int n0 = xx * 64, k0 = yy * 64;
    const int row = threadIdx.x >> 2, seg = (threadIdx.x & 3) << 4;
    const float* src = in + (long)(k0 + row) * N + n0 + seg;
#pragma unroll
    for (int u = 0; u < 16; u += 4) {
        float4 x = *(const float4*)(src + u);
        t[(seg + u + 0) * 72 + row] = (__bf16)x.x;
        t[(seg + u + 1) * 72 + row] = (__bf16)x.y;
        t[(seg + u + 2) * 72 + row] = (__bf16)x.z;
        t[(seg + u + 3) * 72 + row] = (__bf16)x.w;
    }
    __syncthreads();
    __bf16* dst = out + (long)(n0 + row) * 1024 + k0 + seg;
    *(uint4*)(dst)     = *(const uint4*)(t + row * 72 + seg);
    *(uint4*)(dst + 8) = *(const uint4*)(t + row * 72 + seg + 8);
}

// ---------------------------------------------------------------------------
// Shared GEMM core: 128x128 tile, BK=32, 4 waves, K-loop with
// global_load_lds + XOR-swizzled LDS.  Accumulates into acc[4][4].
// ---------------------------------------------------------------------------
__device__ __forceinline__ void gemm_core(
    const __bf16* __restrict__ A, const __bf16* __restrict__ BT,
    __bf16* As, __bf16* Bs, int m0, int n0, int K, f32x4 (&acc)[4][4])
{
    const int tid = threadIdx.x, w = tid >> 6, l = tid & 63;
    const int il = l & 15, quad = l >> 4;
    const int wm = (w >> 1) * 64, wn = (w & 1) * 64;
    const int lr = l >> 2, kc = (l & 3) ^ (lr & 3);

    const __bf16* ag = A  + (long)(m0 + w * 32 + lr) * K + kc * 8;
    const __bf16* bg = BT + (long)(n0 + w * 32 + lr) * K + kc * 8;
    __bf16* al0 = As + (w * 32) * 32;
    __bf16* al1 = As + (w * 32 + 16) * 32;
    __bf16* bl0 = Bs + (w * 32) * 32;
    __bf16* bl1 = Bs + (w * 32 + 16) * 32;
    const int rsw = il & 3;

    for (int k0 = 0; k0 < K; k0 += 32) {
        __syncthreads();
        g2l16(al0, ag + k0);
        g2l16(al1, ag + k0 + 16 * K);
        g2l16(bl0, bg + k0);
        g2l16(bl1, bg + k0 + 16 * K);
        __syncthreads();

        bf16x8 af[4], bf[4];
#pragma unroll
        for (int f = 0; f < 4; ++f) {
            af[f] = *(const bf16x8*)(As + (wm + f * 16 + il) * 32 + ((quad ^ rsw) << 3));
            bf[f] = *(const bf16x8*)(Bs + (wn + f * 16 + il) * 32 + ((quad ^ rsw) << 3));
        }
#pragma unroll
        for (int i = 0; i < 4; ++i)
#pragma unroll
            for (int j = 0; j < 4; ++j)
                acc[i][j] = __builtin_amdgcn_mfma_f32_16x16x32_bf16(
                    af[i], bf[j], acc[i][j], 0, 0, 0);
    }
}

// ---------------------------------------------------------------------------
// Merged projection GEMM: 1408 blocks.
//   [0,1024):  kv = w @ Wkv   -> kh / vhT   (16x16x4 tiles)
//   [1024,1280): q = w[:,-QL:] @ Wq -> qwh/qrh (+biases)  (8x8x4)
//   [1280,1408): rk = r @ Wr  -> rkh        (8x16)
// ---------------------------------------------------------------------------
__global__ __launch_bounds__(256, 2)
void gemm_proj(const __bf16* __restrict__ wbh, const __bf16* __restrict__ rbh,
               const __bf16* __restrict__ WqT, const __bf16* __restrict__ WkvT,
               const __bf16* __restrict__ WrT,
               __bf16* __restrict__ qwh, __bf16* __restrict__ qrh,
               __bf16* __restrict__ kh, __bf16* __restrict__ vhT,
               __bf16* __restrict__ rkh,
               const float* __restrict__ bw, const float* __restrict__ br)
{
    __shared__ __bf16 As[128 * 32];
    __shared__ __bf16 Bs[128 * 32];
    const int id = blockIdx.x;
    const __bf16 *A, *BT;
    int m0, n0, zz, kind;
    if (id < 1024) {
        n0 = (id & 15) * 128; m0 = ((id >> 4) & 15) * 128; zz = id >> 8;
        A = wbh + (size_t)zz * KLN * DM; BT = WkvT; kind = 3;
    } else if (id < 1280) {
        const int t = id - 1024;
        n0 = (t & 7) * 128; m0 = ((t >> 3) & 7) * 128; zz = t >> 6;
        A = wbh + (size_t)zz * KLN * DM + (size_t)MEM * DM; BT = WqT; kind = 2;
    } else {
        const int t = id - 1280;
        n0 = (t & 7) * 128; m0 = (t >> 3) * 128; zz = 0;
        A = rbh; BT = WrT; kind = 4;
    }

    f32x4 acc[4][4] = {};
    gemm_core(A, BT, As, Bs, m0, n0, DM, acc);

    const int tid = threadIdx.x, w = tid >> 6, l = tid & 63;
    const int il = l & 15, quad = l >> 4;
    const int wm = (w >> 1) * 64, wn = (w & 1) * 64;

    if (kind == 2) {
#pragma unroll
        for (int j = 0; j < 4; ++j) {
            const int col = n0 + wn + j * 16 + il;
            const int hn = col >> 6, d = col & 63;
            const float bwv = bw[col], brv = br[col];
            __bf16* q1 = qwh + ((size_t)(zz * 16 + hn) * 1024) * 64 + d;
            __bf16* q2 = qrh + ((size_t)(zz * 16 + hn) * 1024) * 64 + d;
#pragma unroll
            for (int i = 0; i < 4; ++i) {
                const int mb = m0 + wm + i * 16 + quad * 4;
#pragma unroll
                for (int rr = 0; rr < 4; ++rr) {
                    float v = acc[i][j][rr];
                    q1[(size_t)(mb + rr) * 64] = (__bf16)(v + bwv);
                    q2[(size_t)(mb + rr) * 64] = (__bf16)(v + brv);
                }
            }
        }
    } else if (kind == 3) {
        if (n0 + wn < 1024) {
#pragma unroll
            for (int j = 0; j < 4; ++j) {
                const int col = n0 + wn + j * 16 + il;
                const int hn = col >> 6, d = col & 63;
                __bf16* kp = kh + ((size_t)(zz * 16 + hn) * 2048) * 64 + d;
#pragma unroll
                for (int i = 0; i < 4; ++i) {
                    const int mb = m0 + wm + i * 16 + quad * 4;
#pragma unroll
                    for (int rr = 0; rr < 4; ++rr)
                        kp[(size_t)(mb + rr) * 64] = (__bf16)acc[i][j][rr];
                }
            }
        } else {
#pragma unroll
            for (int j = 0; j < 4; ++j) {
                const int col = n0 + wn + j * 16 + il - 1024;
                const int hn = col >> 6, d = col & 63;
                __bf16* vp = vhT + ((size_t)((zz * 16 + hn) * 64 + d)) * 2048;
#pragma unroll
                for (int i = 0; i < 4; ++i) {
                    const int mb = m0 + wm + i * 16 + quad * 4;
                    bf16x4t pk = {(__bf16)acc[i][j][0], (__bf16)acc[i][j][1],
                                  (__bf16)acc[i][j][2], (__bf16)acc[i][j][3]};
                    *(bf16x4t*)(vp + mb) = pk;
                }
            }
        }
    } else { // kind 4
#pragma unroll
        for (int j = 0; j < 4; ++j) {
            const int col = n0 + wn + j * 16 + il;
            const int hn = col >> 6, d = col & 63;
            __bf16* rp = rkh + ((size_t)hn * 2048) * 64 + d;
#pragma unroll
            for (int i = 0; i < 4; ++i) {
                const int mb = m0 + wm + i * 16 + quad * 4;
#pragma unroll
                for (int rr = 0; rr < 4; ++rr)
                    rp[(size_t)(mb + rr) * 64] = (__bf16)acc[i][j][rr];
            }
        }
    }
}

// ---------------------------------------------------------------------------
// Output projection: out = avh @ WoT^T, f32 C.  Grid (8,8,4).
// ---------------------------------------------------------------------------
__global__ __launch_bounds__(256, 2)
void gemm_out(const __bf16* __restrict__ avh, const __bf16* __restrict__ WoT,
              float* __restrict__ C)
{
    __shared__ __bf16 As[128 * 32];
    __shared__ __bf16 Bs[128 * 32];
    const int zz = blockIdx.z;
    const __bf16* A = avh + (size_t)zz * QL * DM;
    const int m0 = blockIdx.y * 128, n0 = blockIdx.x * 128;

    f32x4 acc[4][4] = {};
    gemm_core(A, WoT, As, Bs, m0, n0, DM, acc);

    const int tid = threadIdx.x, w = tid >> 6, l = tid & 63;
    const int il = l & 15, quad = l >> 4;
    const int wm = (w >> 1) * 64, wn = (w & 1) * 64;
    float* Cb = C + (size_t)zz * QL * DM;
#pragma unroll
    for (int i = 0; i < 4; ++i)
#pragma unroll
        for (int j = 0; j < 4; ++j) {
            float* cp = Cb + (long)(m0 + wm + i * 16 + quad * 4) * DM
                           + n0 + wn + j * 16 + il;
#pragma unroll
            for (int rr = 0; rr < 4; ++rr) cp[(long)rr * DM] = acc[i][j][rr];
        }
}

// ---------------------------------------------------------------------------
// MFMA flash attention, R8: 128-i blocks with REGISTER-DEDUPED frag reads.
// All kt/vt/rkt fragments are loaded into VGPRs once per tile and feed both
// i-groups' MFMAs (b128 LDS reads/tile/wave: 52 -> 28).  Phases per tile:
//   1) AC both g   2) BD both g (6 shared rkt frags; stores to per-g scratch)
//   3) per g: diag-gather+mask -> softmax -> P store -> PV (vt frags shared).
// rkt: 192-row circular window (rot in {0,64,128}), slide 64 rows/tile.
// Per-(wave,g) scratch [16][88] unions Btilde (u 0..79) and P (j 0..63).
// LDS: kt 8KB | vt 8KB | rkt 24KB | scratch 22KB = 63488 B -> 2 blocks/CU.
// ---------------------------------------------------------------------------
__global__ __launch_bounds__(256, 2)
void attn_mfma(const __bf16* __restrict__ qwh, const __bf16* __restrict__ qrh,
               const __bf16* __restrict__ kh, const __bf16* __restrict__ vhT,
               const __bf16* __restrict__ rkh, float* __restrict__ Op,
               float* __restrict__ ml)
{
    extern __shared__ __bf16 smem[];
    __bf16* kt  = smem;            // [64][64] xor-swizzled
    __bf16* vt  = smem + 4096;     // [64][64] xor
    __bf16* rkt = smem + 8192;     // [192][64] xor, circular
    __bf16* sc  = smem + 20480;    // 4 waves x 2 g x 1408 elems

    const int bx = blockIdx.x;
    const int part = bx & 1;
    const int bx2 = bx >> 1;                     // 0..7
    const int ib = (bx2 & 1) ? (7 - (bx2 >> 1)) : (bx2 >> 1);
    const int i0 = ib * 128;
    const int n = blockIdx.y, b = blockIdx.z;
    const int tid = threadIdx.x;
    const int w = tid >> 6, l = tid & 63;
    const int il = l & 15, quad = l >> 4;
    const int iw0 = i0 + w * 32;

    // persistent Q fragments, 2 i-frags per wave
    bf16x8 qwf[2][2], qrf[2][2];
#pragma unroll
    for (int g = 0; g < 2; ++g) {
        const size_t qoff =
            ((size_t)((b * 16 + n) * QL + iw0 + 16 * g + il)) * 64 + quad * 8;
        qwf[g][0] = *(const bf16x8*)(qwh + qoff);
        qwf[g][1] = *(const bf16x8*)(qwh + qoff + 32);
        qrf[g][0] = *(const bf16x8*)(qrh + qoff);
        qrf[g][1] = *(const bf16x8*)(qrh + qoff + 32);
    }

    f32x4 O[2][4] = {};
    float m_i[2] = {-1e30f, -1e30f}, l_i[2] = {0.f, 0.f};
    const float c = 0.125f * 1.44269504f;        // scale * log2(e)

    const int srow = l >> 3, scl = l & 7;        // staging: 8 rows x 8 chunks
    const __bf16* kbase  = kh  + ((size_t)((b * 16 + n) * KLN)) * 64;
    const __bf16* vbase0 = vhT + ((size_t)((b * 16 + n) * 64)) * KLN;
    const __bf16* rbp    = rkh + ((size_t)(n * KLN)) * 64;

    const int xk0 = ((quad) ^ (il & 7)) << 3;
    const int xk1 = ((quad + 4) ^ (il & 7)) << 3;

    const int nt = 2 * ib + 18;
    const int t0 = (part * nt) / 2;
    const int t1 = ((part + 1) * nt) / 2;
    int rot = (t0 % 3) * 64;                     // circular offset for tile t0

    const int ubB = 96 - 32 * w;                 // logical base of shared BD frags

    for (int jt = t0; jt < t1; ++jt) {
        const int j0 = jt * 64;
        const int vu0 = j0 - i0 + 896;           // rk row of logical rkt row 0
        __syncthreads();
#pragma unroll
        for (int it = 0; it < 2; ++it) {         // K tile rows j
            const int row = w * 16 + it * 8 + srow;
            g2l16(kt + (w * 16 + it * 8) * 64,
                  kbase + ((size_t)(j0 + row)) * 64 + ((scl ^ srow) << 3));
        }
#pragma unroll
        for (int it = 0; it < 2; ++it) {         // V^T tile rows d
            const int row = w * 16 + it * 8 + srow;
            g2l16(vt + (w * 16 + it * 8) * 64,
                  vbase0 + (size_t)row * KLN + j0 + ((scl ^ srow) << 3));
        }
        if (jt == t0) {                          // full 192-row window fill
#pragma unroll
            for (int it = 0; it < 6; ++it) {
                const int lbase = w * 48 + it * 8;
                int pb = lbase + rot; if (pb >= 192) pb -= 192;
                int vu = vu0 + lbase + srow;
                vu = vu < 0 ? 0 : (vu > KLN - 1 ? KLN - 1 : vu);
                g2l16(rkt + pb * 64,
                      rbp + (size_t)vu * 64 + ((scl ^ srow) << 3));
            }
        } else {                                 // slide: logical rows 128..191
#pragma unroll
            for (int it = 0; it < 2; ++it) {
                const int lbase = 128 + w * 16 + it * 8;
                int pb = lbase + rot; if (pb >= 192) pb -= 192;
                int vu = vu0 + lbase + srow;
                vu = vu < 0 ? 0 : (vu > KLN - 1 ? KLN - 1 : vu);
                g2l16(rkt + pb * 64,
                      rbp + (size_t)vu * 64 + ((scl ^ srow) << 3));
            }
        }
        __syncthreads();

        const bool edge = (j0 + 63 > i0 + MEM);

        // ---- Phase 1: AC for both g (kt frags read ONCE)
        f32x4 sf[2][4];
#pragma unroll
        for (int fr = 0; fr < 4; ++fr) {
            const __bf16* ka = kt + (fr * 16 + il) * 64;
            bf16x8 a0 = *(const bf16x8*)(ka + xk0);
            bf16x8 a1 = *(const bf16x8*)(ka + xk1);
#pragma unroll
            for (int g = 0; g < 2; ++g) {
                f32x4 acc = {};
                acc = __builtin_amdgcn_mfma_f32_16x16x32_bf16(a0, qwf[g][0], acc, 0, 0, 0);
                acc = __builtin_amdgcn_mfma_f32_16x16x32_bf16(a1, qwf[g][1], acc, 0, 0, 0);
                sf[g][fr] = acc;
            }
        }

        // ---- Phase 2: BD for both g; 6 shared rkt frags (g0: 1..5, g1: 0..4)
        {
            bf16x8 ra[6][2];
#pragma unroll
            for (int uf2 = 0; uf2 < 6; ++uf2) {
                int pr = ubB + uf2 * 16 + il + rot; if (pr >= 192) pr -= 192;
                const __bf16* rp_ = rkt + pr * 64;
                ra[uf2][0] = *(const bf16x8*)(rp_ + xk0);
                ra[uf2][1] = *(const bf16x8*)(rp_ + xk1);
            }
#pragma unroll
            for (int g = 0; g < 2; ++g) {
                __bf16* scg = sc + (w * 2 + g) * 1408;
#pragma unroll
                for (int uf = 0; uf < 5; ++uf) {
                    const int idx = uf + 1 - g;
                    f32x4 acc = {};
                    acc = __builtin_amdgcn_mfma_f32_16x16x32_bf16(ra[idx][0], qrf[g][0], acc, 0, 0, 0);
                    acc = __builtin_amdgcn_mfma_f32_16x16x32_bf16(ra[idx][1], qrf[g][1], acc, 0, 0, 0);
                    bf16x4t bb = {(__bf16)acc[0], (__bf16)acc[1],
                                  (__bf16)acc[2], (__bf16)acc[3]};
                    *(bf16x4t*)(scg + il * 88 + uf * 16 + quad * 4) = bb;
                }
            }
        }

        // ---- Phase 3: per-g gather/softmax/P/PV (vt frags read ONCE)
        bf16x8 va[4][2];
#pragma unroll
        for (int df = 0; df < 4; ++df) {
            const __bf16* vp_ = vt + (df * 16 + il) * 64;
            va[df][0] = *(const bf16x8*)(vp_ + xk0);
            va[df][1] = *(const bf16x8*)(vp_ + xk1);
        }
#pragma unroll
        for (int g = 0; g < 2; ++g) {
            __bf16* scg = sc + (w * 2 + g) * 1408;
            const int i_gl = iw0 + 16 * g + il;

            float sv[4][4];
            float tmax = -1e30f;
#pragma unroll
            for (int fr = 0; fr < 4; ++fr)
#pragma unroll
                for (int rr = 0; rr < 4; ++rr) {
                    const int jl_ = fr * 16 + quad * 4 + rr;
                    float s = sf[g][fr][rr] + (float)scg[il * 88 + (jl_ - il + 15)];
                    if (edge) s = (j0 + jl_ > i_gl + MEM) ? -1e30f : s;
                    sv[fr][rr] = s;
                    tmax = fmaxf(tmax, s);
                }
            tmax = fmaxf(tmax, __shfl_xor(tmax, 16));
            tmax = fmaxf(tmax, __shfl_xor(tmax, 32));
            const float m_new = fmaxf(m_i[g], tmax);
            const float alpha = exp2f((m_i[g] - m_new) * c);
            float psum = 0.f;
#pragma unroll
            for (int fr = 0; fr < 4; ++fr) {
                bf16x4t p4;
#pragma unroll
                for (int rr = 0; rr < 4; ++rr) {
                    float p = exp2f((sv[fr][rr] - m_new) * c);
                    psum += p;
                    p4[rr] = (__bf16)p;
                }
                // overwrites bt region of THIS g only (own scratch): safe
                *(bf16x4t*)(scg + il * 88 + fr * 16 + quad * 4) = p4;
            }
            psum += __shfl_xor(psum, 16);
            psum += __shfl_xor(psum, 32);
            l_i[g] = l_i[g] * alpha + psum;
            m_i[g] = m_new;
#pragma unroll
            for (int df = 0; df < 4; ++df) O[g][df] *= alpha;

            bf16x8 p0 = *(const bf16x8*)(scg + il * 88 + quad * 8);
            bf16x8 p1 = *(const bf16x8*)(scg + il * 88 + 32 + quad * 8);
#pragma unroll
            for (int df = 0; df < 4; ++df) {
                O[g][df] = __builtin_amdgcn_mfma_f32_16x16x32_bf16(va[df][0], p0, O[g][df], 0, 0, 0);
                O[g][df] = __builtin_amdgcn_mfma_f32_16x16x32_bf16(va[df][1], p1, O[g][df], 0, 0, 0);
            }
        }
        rot += 64; if (rot >= 192) rot -= 192;
    }

    // ---- write partials (unnormalized)
#pragma unroll
    for (int g = 0; g < 2; ++g) {
        const int iL = w * 32 + 16 * g + il;
        float* opb = Op + (size_t)part * 4194304
                        + ((((size_t)b * NH + n) * 8 + ib)) * 8192
                        + (size_t)iL * 64 + quad * 4;
#pragma unroll
        for (int df = 0; df < 4; ++df)
            *(f32x4*)(opb + df * 16) = O[g][df];
        if (quad == 0) {
            const size_t base = (((size_t)b * NH + n) * 8 + ib) * 128 + iL;
            ml[(size_t)part * 65536 + base]          = m_i[g];
            ml[131072 + (size_t)part * 65536 + base] = l_i[g];
        }
    }
}

// ---------------------------------------------------------------------------
// Combine 2 attention partials -> avh bf16.  Grid (QL/4, NH, BSZ).
// ---------------------------------------------------------------------------
__global__ __launch_bounds__(256)
void attn_combine(const float* __restrict__ Op, const float* __restrict__ ml,
                  __bf16* __restrict__ av)
{
    const int tid = threadIdx.x;
    const int i = blockIdx.x * 4 + (tid >> 6);
    const int d = tid & 63;
    const int n = blockIdx.y, b = blockIdx.z;
    const int ib = i >> 7, iL = i & 127;
    const float c = 0.125f * 1.44269504f;

    const size_t mb = (((size_t)b * NH + n) * 8 + ib) * 128 + iL;
    const float m0 = ml[mb], m1 = ml[mb + 65536];
    const float l0 = ml[131072 + mb], l1 = ml[131072 + 65536 + mb];
    const float ms = fmaxf(m0, m1);
    const float w0 = exp2f((m0 - ms) * c);
    const float w1 = exp2f((m1 - ms) * c);
    const float ls = w0 * l0 + w1 * l1;

    const size_t ob = (((size_t)b * NH + n) * 8 + ib) * 8192
                      + (size_t)iL * 64 + d;
    const float o = w0 * Op[ob] + w1 * Op[ob + 4194304];
    av[((size_t)(b * QL + i)) * DM + n * 64 + d] = (__bf16)(o / ls);
}

// ---------------------------------------------------------------------------
// Workspace (MB offsets, ~123 MB total):
//  0 wbh(16) | 16 rbh(4) | 20 WqT(2) | 22 WkvT(4) | 26 WrT(2) | 28 WoT(2)
//  30 qwh(8) | 38 qrh(8) | 46 kh(16) | 62 vhT(16) | 78 rkh(4) | 82 avh(8)
//  90 Op(32) | 122 ml(1)
// ---------------------------------------------------------------------------
extern "C" void kernel_launch(void* const* d_in, const int* in_sizes, int n_in,
                              void* d_out, int out_size, void* d_ws, size_t ws_size,
                              hipStream_t stream)
{
    const float* w   = (const float*)d_in[0];
    const float* r   = (const float*)d_in[1];
    const float* bwb = (const float*)d_in[2];
    const float* brb = (const float*)d_in[3];
    const float* Wq  = (const float*)d_in[4];
    const float* Wkv = (const float*)d_in[5];
    const float* Wr  = (const float*)d_in[6];
    const float* Wo  = (const float*)d_in[7];
    float* out = (float*)d_out;

    char* ws = (char*)d_ws;
    __bf16* wbh  = (__bf16*)(ws);
    __bf16* rbh  = (__bf16*)(ws + ((size_t)16 << 20));
    __bf16* WqT  = (__bf16*)(ws + ((size_t)20 << 20));
    __bf16* WkvT = (__bf16*)(ws + ((size_t)22 << 20));
    __bf16* WrT  = (__bf16*)(ws + ((size_t)26 << 20));
    __bf16* WoT  = (__bf16*)(ws + ((size_t)28 << 20));
    __bf16* qwh  = (__bf16*)(ws + ((size_t)30 << 20));
    __bf16* qrh  = (__bf16*)(ws + ((size_t)38 << 20));
    __bf16* kh   = (__bf16*)(ws + ((size_t)46 << 20));
    __bf16* vhT  = (__bf16*)(ws + ((size_t)62 << 20));
    __bf16* rkh  = (__bf16*)(ws + ((size_t)78 << 20));
    __bf16* avh  = (__bf16*)(ws + ((size_t)82 << 20));
    float*  Op   = (float*)(ws + ((size_t)90 << 20));
    float*  mlb  = (float*)(ws + ((size_t)122 << 20));

    dim3 blk(256);
    prep<<<7168, blk, 0, stream>>>(w, r, Wq, Wr, Wo, Wkv,
                                   wbh, rbh, WqT, WrT, WoT, WkvT);
    gemm_proj<<<1408, blk, 0, stream>>>(wbh, rbh, WqT, WkvT, WrT,
                                        qwh, qrh, kh, vhT, rkh, bwb, brb);
    attn_mfma<<<dim3(16, 16, 4), blk, 63488, stream>>>(
        qwh, qrh, kh, vhT, rkh, Op, mlb);
    attn_combine<<<dim3(256, 16, 4), blk, 0, stream>>>(Op, mlb, avh);
    gemm_out<<<dim3(8, 8, 4), blk, 0, stream>>>(avh, WoT, out);
}